// Round 2
// baseline (6206.905 us; speedup 1.0000x reference)
//
#include <hip/hip_runtime.h>
#include <hip/hip_bf16.h>

#define N_NODES 163840
#define N_EDGES 2621440
#define NB      4096

typedef __hip_bfloat16 bf16;

__device__ inline float tofloat(float v) { return v; }
__device__ inline float tofloat(bf16 v) { return __bfloat162float(v); }
__device__ inline void storev(float* p, float v) { *p = v; }
__device__ inline void storev(bf16* p, float v) { *p = __float2bfloat16(v); }

// ======================= graph preprocessing =======================

__global__ __launch_bounds__(256) void zero_kernel(int* __restrict__ p) {
  p[blockIdx.x * 256 + threadIdx.x] = 0;
}

__global__ __launch_bounds__(256) void count_kernel(const int* __restrict__ ei,
                                                    int* __restrict__ indeg) {
  int e = blockIdx.x * 256 + threadIdx.x;
  if (e < N_EDGES) atomicAdd(&indeg[ei[N_EDGES + e]], 1);
}

__global__ __launch_bounds__(256) void dinv_kernel(const int* __restrict__ indeg,
                                                   float* __restrict__ dinv) {
  int i = blockIdx.x * 256 + threadIdx.x;
  if (i < N_NODES) dinv[i] = rsqrtf((float)indeg[i] + 1.0f);
}

__global__ __launch_bounds__(256) void scan1_kernel(const int* __restrict__ indeg,
                                                    int* __restrict__ rowstart,
                                                    int* __restrict__ bsums) {
  __shared__ int s[256];
  int tid = threadIdx.x;
  int i = blockIdx.x * 256 + tid;
  int v = indeg[i];
  s[tid] = v;
  __syncthreads();
  for (int off = 1; off < 256; off <<= 1) {
    int x = (tid >= off) ? s[tid - off] : 0;
    __syncthreads();
    s[tid] += x;
    __syncthreads();
  }
  rowstart[i] = s[tid] - v;  // exclusive within block
  if (tid == 255) bsums[blockIdx.x] = s[255];
}

__global__ void scan2_kernel(const int* __restrict__ bsums, int* __restrict__ boffs,
                             int* __restrict__ rowstart) {
  if (threadIdx.x == 0 && blockIdx.x == 0) {
    int run = 0;
    for (int i = 0; i < 640; i++) { boffs[i] = run; run += bsums[i]; }
    rowstart[N_NODES] = run;  // == N_EDGES
  }
}

__global__ __launch_bounds__(256) void scan3_kernel(int* __restrict__ rowstart,
                                                    int* __restrict__ cursor,
                                                    const int* __restrict__ boffs) {
  int i = blockIdx.x * 256 + threadIdx.x;
  int v = rowstart[i] + boffs[blockIdx.x];
  rowstart[i] = v;
  cursor[i] = v;
}

__global__ __launch_bounds__(256) void scatter_kernel(const int* __restrict__ ei,
                                                      int* __restrict__ cursor,
                                                      int* __restrict__ csr_src) {
  int e = blockIdx.x * 256 + threadIdx.x;
  if (e < N_EDGES) {
    int s = ei[e], d = ei[N_EDGES + e];
    int pos = atomicAdd(&cursor[d], 1);
    csr_src[pos] = s;
  }
}

__global__ __launch_bounds__(256) void cast_kernel(const float* __restrict__ x,
                                                   bf16* __restrict__ xb) {
  int i = blockIdx.x * 256 + threadIdx.x;
  xb[i] = __float2bfloat16(x[i]);
}

// ======================= GCN aggregation (no bias/relu; those fused into gemm) =====
// out[n,f] = dn * sum_{e:dst=n} h[src_e,f]*dinv[src] + h[n,f]*dn^2,  dn = dinv[n]
template <int NR>
__global__ __launch_bounds__(256) void agg_kernel(const bf16* __restrict__ h,
                                                  const float* __restrict__ dinv,
                                                  const int* __restrict__ rowstart,
                                                  const int* __restrict__ csr,
                                                  bf16* __restrict__ out, int F) {
  int node = blockIdx.x * 4 + (threadIdx.x >> 6);
  int lane = threadIdx.x & 63;
  float acc[NR];
#pragma unroll
  for (int r = 0; r < NR; r++) acc[r] = 0.f;
  int st = rowstart[node], en = rowstart[node + 1];
  float dn = dinv[node];
  for (int e = st; e < en; e++) {
    int s = csr[e];
    float w = dinv[s];
    const bf16* hr = h + (size_t)s * F;
#pragma unroll
    for (int r = 0; r < NR; r++) {
      int f = lane + 64 * r;
      if (f < F) acc[r] += tofloat(hr[f]) * w;
    }
  }
  float sn = dn * dn;
  const bf16* hn = h + (size_t)node * F;
  bf16* on = out + (size_t)node * F;
#pragma unroll
  for (int r = 0; r < NR; r++) {
    int f = lane + 64 * r;
    if (f < F) {
      float v = acc[r] * dn + tofloat(hn[f]) * sn;
      on[f] = __float2bfloat16(v);
    }
  }
}

// ======================= generic SGEMM (A: TA, B: f32, C: TC) =======================
// C[row, coff+col] = act(A[M,K] @ B[K,Nc] + bias)
template <typename TA, typename TC>
__global__ __launch_bounds__(256) void sgemm_kernel(const TA* __restrict__ A,
                                                    const float* __restrict__ Bm,
                                                    const float* __restrict__ bias,
                                                    TC* __restrict__ C, int M, int Nc,
                                                    int K, int ldc, int coff, int doRelu) {
  __shared__ float As[16][65];
  __shared__ float Bs[16][65];
  int tid = threadIdx.x;
  int tx = tid & 15, ty = tid >> 4;
  int rowBase = blockIdx.y * 64;
  int colBase = blockIdx.x * 64;
  float acc[4][4] = {};
  for (int k0 = 0; k0 < K; k0 += 16) {
    {
      int kk = tid & 15;
      int r0 = tid >> 4;
#pragma unroll
      for (int j = 0; j < 4; j++) {
        int r = r0 + 16 * j;
        int grow = rowBase + r, gk = k0 + kk;
        As[kk][r] = (grow < M && gk < K) ? tofloat(A[(size_t)grow * K + gk]) : 0.f;
      }
      int c = tid & 63;
      int kk2 = tid >> 6;
#pragma unroll
      for (int j = 0; j < 4; j++) {
        int k = kk2 + 4 * j;
        int gcol = colBase + c, gk = k0 + k;
        Bs[k][c] = (gk < K && gcol < Nc) ? Bm[(size_t)gk * Nc + gcol] : 0.f;
      }
    }
    __syncthreads();
#pragma unroll
    for (int kk = 0; kk < 16; kk++) {
      float ar[4], br[4];
#pragma unroll
      for (int i = 0; i < 4; i++) ar[i] = As[kk][ty * 4 + i];
#pragma unroll
      for (int j = 0; j < 4; j++) br[j] = Bs[kk][tx * 4 + j];
#pragma unroll
      for (int i = 0; i < 4; i++)
#pragma unroll
        for (int j = 0; j < 4; j++) acc[i][j] += ar[i] * br[j];
    }
    __syncthreads();
  }
#pragma unroll
  for (int i = 0; i < 4; i++) {
    int row = rowBase + ty * 4 + i;
    if (row >= M) continue;
#pragma unroll
    for (int j = 0; j < 4; j++) {
      int col = colBase + tx * 4 + j;
      if (col >= Nc) continue;
      float v = acc[i][j];
      if (bias) v += bias[col];
      if (doRelu) v = fmaxf(v, 0.f);
      storev(&C[(size_t)row * ldc + coff + col], v);
    }
  }
}

// ======= fused layer-3 GCN transform + bias + relu + segment-max (40 nodes/graph) ====
// g[gb,f] = relu( max_n (agg2[gb*40+n,:] @ W3[:,f]) + b3[f] )
__global__ __launch_bounds__(320) void gcn3_segmax_kernel(const bf16* __restrict__ agg2,
                                                          const float* __restrict__ W3,
                                                          const float* __restrict__ b3,
                                                          float* __restrict__ g) {
  __shared__ float a[40][156];  // 24.96 KB
  int gb = blockIdx.x, tid = threadIdx.x;
  for (int i = tid; i < 40 * 156; i += 320)
    a[i / 156][i % 156] = tofloat(agg2[(size_t)gb * (40 * 156) + i]);
  __syncthreads();
  if (tid < 312) {
    float acc[40];
#pragma unroll
    for (int n = 0; n < 40; n++) acc[n] = 0.f;
    for (int k = 0; k < 156; k += 4) {
      float w0 = W3[(size_t)k * 312 + tid];
      float w1 = W3[(size_t)(k + 1) * 312 + tid];
      float w2 = W3[(size_t)(k + 2) * 312 + tid];
      float w3 = W3[(size_t)(k + 3) * 312 + tid];
#pragma unroll
      for (int n = 0; n < 40; n++) {
        float4 av = *(const float4*)&a[n][k];
        acc[n] += av.x * w0 + av.y * w1 + av.z * w2 + av.w * w3;
      }
    }
    float m = acc[0];
#pragma unroll
    for (int n = 1; n < 40; n++) m = fmaxf(m, acc[n]);
    g[gb * 312 + tid] = fmaxf(m + b3[tid], 0.f);
  }
}

// ======================= conv towers (fused bias+relu+pool3) =======================
// conv1: [B,1,735] f32 -> [B,32,242] bf16
__global__ __launch_bounds__(256) void conv1_kernel(const float* __restrict__ xo,
                                                    const float* __restrict__ k1,
                                                    const float* __restrict__ kb1,
                                                    bf16* __restrict__ out) {
  __shared__ float xin[735];
  __shared__ float w[256];
  __shared__ float bb[32];
  int b = blockIdx.x, tid = threadIdx.x;
  for (int i = tid; i < 735; i += 256) xin[i] = xo[b * 735 + i];
  w[tid] = k1[tid];
  if (tid < 32) bb[tid] = kb1[tid];
  __syncthreads();
  for (int idx = tid; idx < 32 * 242; idx += 256) {
    int co = idx / 242, l = idx % 242;
    int base = l * 3;
    float bs = bb[co];
    float a0 = bs, a1 = bs, a2 = bs;
#pragma unroll
    for (int k = 0; k < 8; k++) {
      float wv = w[co * 8 + k];
      a0 += wv * xin[base + k];
      a1 += wv * xin[base + 1 + k];
      a2 += wv * xin[base + 2 + k];
    }
    out[(size_t)(b * 32 + co) * 242 + l] =
        __float2bfloat16(fmaxf(0.f, fmaxf(a0, fmaxf(a1, a2))));
  }
}

// conv2: [B,32,242] bf16 -> [B,64,78] bf16; grid (B, 2), 32 out-channels per block
__global__ __launch_bounds__(256) void conv2_kernel(const bf16* __restrict__ in,
                                                    const float* __restrict__ k2,
                                                    const float* __restrict__ kb2,
                                                    bf16* __restrict__ out) {
  __shared__ float xin[32 * 242];     // 30976 B
  __shared__ float w[32 * 32 * 8];    // 32768 B
  __shared__ float bb[32];
  int b = blockIdx.x, co0 = blockIdx.y * 32, tid = threadIdx.x;
  for (int i = tid; i < 32 * 242; i += 256) xin[i] = tofloat(in[(size_t)b * (32 * 242) + i]);
  for (int i = tid; i < 32 * 32 * 8; i += 256) w[i] = k2[co0 * (32 * 8) + i];
  if (tid < 32) bb[tid] = kb2[co0 + tid];
  __syncthreads();
  for (int idx = tid; idx < 32 * 78; idx += 256) {
    int co = idx / 78, l = idx % 78;
    int base = l * 3;
    float bs = bb[co];
    float a0 = bs, a1 = bs, a2 = bs;
    for (int ci = 0; ci < 32; ci++) {
      const float* xr = &xin[ci * 242 + base];
      const float* wr = &w[(co * 32 + ci) * 8];
#pragma unroll
      for (int k = 0; k < 8; k++) {
        float wv = wr[k];
        a0 += wv * xr[k];
        a1 += wv * xr[k + 1];
        a2 += wv * xr[k + 2];
      }
    }
    out[(size_t)(b * 64 + co0 + co) * 78 + l] =
        __float2bfloat16(fmaxf(0.f, fmaxf(a0, fmaxf(a1, a2))));
  }
}

// conv3: [B,64,78] bf16 -> [B,2944] bf16 flat; grid (B, 8), 16 co per block
__global__ __launch_bounds__(256) void conv3_kernel(const bf16* __restrict__ in,
                                                    const float* __restrict__ k3,
                                                    const float* __restrict__ kb3,
                                                    bf16* __restrict__ out) {
  __shared__ float xin[64 * 78];     // 19968 B
  __shared__ float w[16 * 64 * 8];   // 32768 B
  __shared__ float bb[16];
  int b = blockIdx.x, co0 = blockIdx.y * 16, tid = threadIdx.x;
  for (int i = tid; i < 64 * 78; i += 256) xin[i] = tofloat(in[(size_t)b * (64 * 78) + i]);
  for (int i = tid; i < 16 * 64 * 8; i += 256) w[i] = k3[co0 * (64 * 8) + i];
  if (tid < 16) bb[tid] = kb3[co0 + tid];
  __syncthreads();
  for (int idx = tid; idx < 16 * 23; idx += 256) {
    int co = idx / 23, l = idx % 23;
    int base = l * 3;
    float bs = bb[co];
    float a0 = bs, a1 = bs, a2 = bs;
    for (int ci = 0; ci < 64; ci++) {
      const float* xr = &xin[ci * 78 + base];
      const float* wr = &w[(co * 64 + ci) * 8];
#pragma unroll
      for (int k = 0; k < 8; k++) {
        float wv = wr[k];
        a0 += wv * xr[k];
        a1 += wv * xr[k + 1];
        a2 += wv * xr[k + 2];
      }
    }
    out[(size_t)b * 2944 + (co0 + co) * 23 + l] =
        __float2bfloat16(fmaxf(0.f, fmaxf(a0, fmaxf(a1, a2))));
  }
}

// ======================= final head =======================
__global__ __launch_bounds__(256) void final_kernel(const float* __restrict__ f2,
                                                    const float* __restrict__ Wo,
                                                    const float* __restrict__ bo,
                                                    float* __restrict__ out) {
  int wid = (blockIdx.x * blockDim.x + threadIdx.x) >> 6;
  int lane = threadIdx.x & 63;
  if (wid >= NB) return;
  float s = f2[wid * 128 + lane] * Wo[lane] + f2[wid * 128 + 64 + lane] * Wo[64 + lane];
  for (int o = 32; o > 0; o >>= 1) s += __shfl_down(s, o);
  if (lane == 0) out[wid] = s + bo[0];
}

// ======================= launch =======================
extern "C" void kernel_launch(void* const* d_in, const int* in_sizes, int n_in,
                              void* d_out, int out_size, void* d_ws, size_t ws_size,
                              hipStream_t stream) {
  const float* x   = (const float*)d_in[0];
  const int*   ei  = (const int*)d_in[1];
  // d_in[2] = batch: contiguous, 40 nodes/graph -- exploited in segmax fusion
  const float* xo  = (const float*)d_in[3];
  const float* W1  = (const float*)d_in[4];  const float* b1  = (const float*)d_in[5];
  const float* W2  = (const float*)d_in[6];  const float* b2  = (const float*)d_in[7];
  const float* W3  = (const float*)d_in[8];  const float* b3  = (const float*)d_in[9];
  const float* Wg1 = (const float*)d_in[10]; const float* bg1 = (const float*)d_in[11];
  const float* Wg2 = (const float*)d_in[12]; const float* bg2 = (const float*)d_in[13];
  const float* k1  = (const float*)d_in[14]; const float* kb1 = (const float*)d_in[15];
  const float* k2  = (const float*)d_in[16]; const float* kb2 = (const float*)d_in[17];
  const float* k3  = (const float*)d_in[18]; const float* kb3 = (const float*)d_in[19];
  const float* Wxt = (const float*)d_in[20]; const float* bxt = (const float*)d_in[21];
  const float* Wf1 = (const float*)d_in[22]; const float* bf1 = (const float*)d_in[23];
  const float* Wf2 = (const float*)d_in[24]; const float* bf2 = (const float*)d_in[25];
  const float* Wo  = (const float*)d_in[26]; const float* bo  = (const float*)d_in[27];
  float* out = (float*)d_out;

  char* ws = (char*)d_ws;
  size_t off = 0;
  auto alloc = [&](size_t bytes) -> void* {
    void* p = ws + off;
    off += (bytes + 255) & ~(size_t)255;
    return p;
  };

  // total workspace ~156 MB
  int*   indeg   = (int*)alloc((size_t)N_NODES * 4);
  float* dinv    = (float*)alloc((size_t)N_NODES * 4);
  int*   rowstart= (int*)alloc((size_t)(N_NODES + 1) * 4);
  int*   cursor  = (int*)alloc((size_t)N_NODES * 4);
  int*   bsums   = (int*)alloc(640 * 4);
  int*   boffs   = (int*)alloc(640 * 4);
  int*   csr     = (int*)alloc((size_t)N_EDGES * 4);                    // 10.5 MB
  bf16*  nb1     = (bf16*)alloc((size_t)N_NODES * 156 * 2);             // 51.1 MB
  bf16*  nb2     = (bf16*)alloc((size_t)NB * 32 * 242 * 2);             // 63.4 MB
  float* g       = (float*)alloc((size_t)NB * 312 * 4);                 // 5.1 MB
  float* g1f1    = (float*)alloc((size_t)NB * 1024 * 4);                // 16.8 MB
  float* gt      = (float*)alloc((size_t)NB * 256 * 4);                 // 4.2 MB
  float* f2      = (float*)alloc((size_t)NB * 128 * 4);                 // 2.1 MB

  bf16* xb = nb2;                 // [N,78]   (dead after aggX)
  bf16* h  = nb2;                 // h1 [N,78], h2 [N,156]
  bf16* ag = nb1;                 // aggX/agg1 [N,78], agg2 [N,156]
  bf16* c1 = nb2;                 // [B,32,242] (h2 dead)
  bf16* c2 = nb1;                 // [B,64,78]  (agg2 dead)
  bf16* c3 = nb2;                 // [B,2944]   (c1 dead)

  // ---- CSR build + degree norm ----
  zero_kernel<<<N_NODES / 256, 256, 0, stream>>>(indeg);
  count_kernel<<<N_EDGES / 256, 256, 0, stream>>>(ei, indeg);
  dinv_kernel<<<N_NODES / 256, 256, 0, stream>>>(indeg, dinv);
  scan1_kernel<<<640, 256, 0, stream>>>(indeg, rowstart, bsums);
  scan2_kernel<<<1, 64, 0, stream>>>(bsums, boffs, rowstart);
  scan3_kernel<<<640, 256, 0, stream>>>(rowstart, cursor, boffs);
  scatter_kernel<<<N_EDGES / 256, 256, 0, stream>>>(ei, cursor, csr);

  // ---- GCN layers (aggregate-first: relu(agg(h) @ W + b)) ----
  cast_kernel<<<N_NODES * 78 / 256, 256, 0, stream>>>(x, xb);
  agg_kernel<2><<<N_NODES / 4, 256, 0, stream>>>(xb, dinv, rowstart, csr, ag, 78);
  sgemm_kernel<bf16, bf16><<<dim3(2, N_NODES / 64), 256, 0, stream>>>(
      ag, W1, b1, h, N_NODES, 78, 78, 78, 0, 1);
  agg_kernel<2><<<N_NODES / 4, 256, 0, stream>>>(h, dinv, rowstart, csr, ag, 78);
  sgemm_kernel<bf16, bf16><<<dim3(3, N_NODES / 64), 256, 0, stream>>>(
      ag, W2, b2, h, N_NODES, 156, 78, 156, 0, 1);
  agg_kernel<3><<<N_NODES / 4, 256, 0, stream>>>(h, dinv, rowstart, csr, ag, 156);
  gcn3_segmax_kernel<<<NB, 320, 0, stream>>>(ag, W3, b3, g);

  // ---- graph head ----
  sgemm_kernel<float, float><<<dim3(16, NB / 64), 256, 0, stream>>>(
      g, Wg1, bg1, g1f1, NB, 1024, 312, 1024, 0, 1);
  sgemm_kernel<float, float><<<dim3(2, NB / 64), 256, 0, stream>>>(
      g1f1, Wg2, bg2, gt, NB, 128, 1024, 256, 0, 0);

  // ---- conv tower ----
  conv1_kernel<<<NB, 256, 0, stream>>>(xo, k1, kb1, c1);
  conv2_kernel<<<dim3(NB, 2), 256, 0, stream>>>(c1, k2, kb2, c2);
  conv3_kernel<<<dim3(NB, 8), 256, 0, stream>>>(c2, k3, kb3, c3);
  sgemm_kernel<bf16, float><<<dim3(2, NB / 64), 256, 0, stream>>>(
      c3, Wxt, bxt, gt, NB, 128, 2944, 256, 128, 0);

  // ---- fused head ----
  sgemm_kernel<float, float><<<dim3(16, NB / 64), 256, 0, stream>>>(
      gt, Wf1, bf1, g1f1, NB, 1024, 256, 1024, 0, 1);
  sgemm_kernel<float, float><<<dim3(2, NB / 64), 256, 0, stream>>>(
      g1f1, Wf2, bf2, f2, NB, 128, 1024, 128, 0, 1);
  final_kernel<<<NB * 64 / 256, 256, 0, stream>>>(f2, Wo, bo, out);
}

// Round 3
// 3477.559 us; speedup vs baseline: 1.7848x; 1.7848x over previous
//
#include <hip/hip_runtime.h>
#include <hip/hip_bf16.h>

#define N_NODES 163840
#define N_EDGES 2621440
#define NB      4096

typedef __hip_bfloat16 bf16;
typedef __attribute__((ext_vector_type(8))) short short8;
typedef __attribute__((ext_vector_type(4))) float floatx4;

__device__ inline float tofloat(float v) { return v; }
__device__ inline float tofloat(bf16 v) { return __bfloat162float(v); }
__device__ inline void storev(float* p, float v) { *p = v; }
__device__ inline void storev(bf16* p, float v) { *p = __float2bfloat16(v); }

// ======================= graph preprocessing =======================

__global__ __launch_bounds__(256) void zero_kernel(int* __restrict__ p) {
  p[blockIdx.x * 256 + threadIdx.x] = 0;
}

__global__ __launch_bounds__(256) void count_kernel(const int* __restrict__ ei,
                                                    int* __restrict__ indeg) {
  int e = blockIdx.x * 256 + threadIdx.x;
  if (e < N_EDGES) atomicAdd(&indeg[ei[N_EDGES + e]], 1);
}

__global__ __launch_bounds__(256) void dinv_kernel(const int* __restrict__ indeg,
                                                   float* __restrict__ dinv) {
  int i = blockIdx.x * 256 + threadIdx.x;
  if (i < N_NODES) dinv[i] = rsqrtf((float)indeg[i] + 1.0f);
}

__global__ __launch_bounds__(256) void scan1_kernel(const int* __restrict__ indeg,
                                                    int* __restrict__ rowstart,
                                                    int* __restrict__ bsums) {
  __shared__ int s[256];
  int tid = threadIdx.x;
  int i = blockIdx.x * 256 + tid;
  int v = indeg[i];
  s[tid] = v;
  __syncthreads();
  for (int off = 1; off < 256; off <<= 1) {
    int x = (tid >= off) ? s[tid - off] : 0;
    __syncthreads();
    s[tid] += x;
    __syncthreads();
  }
  rowstart[i] = s[tid] - v;  // exclusive within block
  if (tid == 255) bsums[blockIdx.x] = s[255];
}

__global__ void scan2_kernel(const int* __restrict__ bsums, int* __restrict__ boffs,
                             int* __restrict__ rowstart) {
  if (threadIdx.x == 0 && blockIdx.x == 0) {
    int run = 0;
    for (int i = 0; i < 640; i++) { boffs[i] = run; run += bsums[i]; }
    rowstart[N_NODES] = run;  // == N_EDGES
  }
}

__global__ __launch_bounds__(256) void scan3_kernel(int* __restrict__ rowstart,
                                                    int* __restrict__ cursor,
                                                    const int* __restrict__ boffs) {
  int i = blockIdx.x * 256 + threadIdx.x;
  int v = rowstart[i] + boffs[blockIdx.x];
  rowstart[i] = v;
  cursor[i] = v;
}

__global__ __launch_bounds__(256) void scatter_kernel(const int* __restrict__ ei,
                                                      int* __restrict__ cursor,
                                                      int* __restrict__ csr_src) {
  int e = blockIdx.x * 256 + threadIdx.x;
  if (e < N_EDGES) {
    int s = ei[e], d = ei[N_EDGES + e];
    int pos = atomicAdd(&cursor[d], 1);
    csr_src[pos] = s;
  }
}

__global__ __launch_bounds__(256) void cast_kernel(const float* __restrict__ x,
                                                   bf16* __restrict__ xb) {
  int i = blockIdx.x * 256 + threadIdx.x;
  xb[i] = __float2bfloat16(x[i]);
}

// ======================= GCN aggregation =======================
// out[n,f] = dn * sum_{e:dst=n} h[src_e,f]*dinv[src] + h[n,f]*dn^2,  dn = dinv[n]
template <int NR>
__global__ __launch_bounds__(256) void agg_kernel(const bf16* __restrict__ h,
                                                  const float* __restrict__ dinv,
                                                  const int* __restrict__ rowstart,
                                                  const int* __restrict__ csr,
                                                  bf16* __restrict__ out, int F) {
  int node = blockIdx.x * 4 + (threadIdx.x >> 6);
  int lane = threadIdx.x & 63;
  float acc[NR];
#pragma unroll
  for (int r = 0; r < NR; r++) acc[r] = 0.f;
  int st = rowstart[node], en = rowstart[node + 1];
  float dn = dinv[node];
  for (int e = st; e < en; e++) {
    int s = csr[e];
    float w = dinv[s];
    const bf16* hr = h + (size_t)s * F;
#pragma unroll
    for (int r = 0; r < NR; r++) {
      int f = lane + 64 * r;
      if (f < F) acc[r] += tofloat(hr[f]) * w;
    }
  }
  float sn = dn * dn;
  const bf16* hn = h + (size_t)node * F;
  bf16* on = out + (size_t)node * F;
#pragma unroll
  for (int r = 0; r < NR; r++) {
    int f = lane + 64 * r;
    if (f < F) {
      float v = acc[r] * dn + tofloat(hn[f]) * sn;
      on[f] = __float2bfloat16(v);
    }
  }
}

// ======================= generic SGEMM (A: TA, B: f32, C: TC) =======================
template <typename TA, typename TC>
__global__ __launch_bounds__(256) void sgemm_kernel(const TA* __restrict__ A,
                                                    const float* __restrict__ Bm,
                                                    const float* __restrict__ bias,
                                                    TC* __restrict__ C, int M, int Nc,
                                                    int K, int ldc, int coff, int doRelu) {
  __shared__ float As[16][65];
  __shared__ float Bs[16][65];
  int tid = threadIdx.x;
  int tx = tid & 15, ty = tid >> 4;
  int rowBase = blockIdx.y * 64;
  int colBase = blockIdx.x * 64;
  float acc[4][4] = {};
  for (int k0 = 0; k0 < K; k0 += 16) {
    {
      int kk = tid & 15;
      int r0 = tid >> 4;
#pragma unroll
      for (int j = 0; j < 4; j++) {
        int r = r0 + 16 * j;
        int grow = rowBase + r, gk = k0 + kk;
        As[kk][r] = (grow < M && gk < K) ? tofloat(A[(size_t)grow * K + gk]) : 0.f;
      }
      int c = tid & 63;
      int kk2 = tid >> 6;
#pragma unroll
      for (int j = 0; j < 4; j++) {
        int k = kk2 + 4 * j;
        int gcol = colBase + c, gk = k0 + k;
        Bs[k][c] = (gk < K && gcol < Nc) ? Bm[(size_t)gk * Nc + gcol] : 0.f;
      }
    }
    __syncthreads();
#pragma unroll
    for (int kk = 0; kk < 16; kk++) {
      float ar[4], br[4];
#pragma unroll
      for (int i = 0; i < 4; i++) ar[i] = As[kk][ty * 4 + i];
#pragma unroll
      for (int j = 0; j < 4; j++) br[j] = Bs[kk][tx * 4 + j];
#pragma unroll
      for (int i = 0; i < 4; i++)
#pragma unroll
        for (int j = 0; j < 4; j++) acc[i][j] += ar[i] * br[j];
    }
    __syncthreads();
  }
#pragma unroll
  for (int i = 0; i < 4; i++) {
    int row = rowBase + ty * 4 + i;
    if (row >= M) continue;
#pragma unroll
    for (int j = 0; j < 4; j++) {
      int col = colBase + tx * 4 + j;
      if (col >= Nc) continue;
      float v = acc[i][j];
      if (bias) v += bias[col];
      if (doRelu) v = fmaxf(v, 0.f);
      storev(&C[(size_t)row * ldc + coff + col], v);
    }
  }
}

// ======= fused layer-3 GCN transform + bias + relu + segment-max (40 nodes/graph) ====
__global__ __launch_bounds__(320) void gcn3_segmax_kernel(const bf16* __restrict__ agg2,
                                                          const float* __restrict__ W3,
                                                          const float* __restrict__ b3,
                                                          float* __restrict__ g) {
  __shared__ float a[40][156];
  int gb = blockIdx.x, tid = threadIdx.x;
  for (int i = tid; i < 40 * 156; i += 320)
    a[i / 156][i % 156] = tofloat(agg2[(size_t)gb * (40 * 156) + i]);
  __syncthreads();
  if (tid < 312) {
    float acc[40];
#pragma unroll
    for (int n = 0; n < 40; n++) acc[n] = 0.f;
    for (int k = 0; k < 156; k += 4) {
      float w0 = W3[(size_t)k * 312 + tid];
      float w1 = W3[(size_t)(k + 1) * 312 + tid];
      float w2 = W3[(size_t)(k + 2) * 312 + tid];
      float w3 = W3[(size_t)(k + 3) * 312 + tid];
#pragma unroll
      for (int n = 0; n < 40; n++) {
        float4 av = *(const float4*)&a[n][k];
        acc[n] += av.x * w0 + av.y * w1 + av.z * w2 + av.w * w3;
      }
    }
    float m = acc[0];
#pragma unroll
    for (int n = 1; n < 40; n++) m = fmaxf(m, acc[n]);
    g[gb * 312 + tid] = fmaxf(m + b3[tid], 0.f);
  }
}

// ======================= weight prep for MFMA convs =======================
// Wr[k*NCO + co], k = dl*CI + ci; source kw[co][ci][dl]
template <int CI, int NCO>
__global__ __launch_bounds__(256) void wprep_kernel(const float* __restrict__ kw,
                                                    bf16* __restrict__ Wr) {
  int idx = blockIdx.x * 256 + threadIdx.x;
  if (idx < 8 * CI * NCO) {
    int co = idx % NCO, k = idx / NCO;
    int dl = k / CI, ci = k % CI;
    Wr[idx] = __float2bfloat16(kw[(co * CI + ci) * 8 + dl]);
  }
}

// Wp[(l*128+co)*128 + o] = Wxt[(co*23+l)*128 + o]
__global__ __launch_bounds__(256) void wxtprep_kernel(const float* __restrict__ Wxt,
                                                      float* __restrict__ Wp) {
  int idx = blockIdx.x * 256 + threadIdx.x;
  if (idx < 2944 * 128) {
    int o = idx & 127, r = idx >> 7;
    int l = r >> 7, co = r & 127;
    Wp[idx] = Wxt[((size_t)(co * 23 + l)) * 128 + o];
  }
}

// ======================= conv1: [B,735] f32 -> [B,242,32] bf16 (pos-major) =========
__global__ __launch_bounds__(256) void conv1_kernel(const float* __restrict__ xo,
                                                    const float* __restrict__ k1,
                                                    const float* __restrict__ kb1,
                                                    bf16* __restrict__ out) {
  __shared__ float xin[735];
  int b = blockIdx.x, tid = threadIdx.x;
  for (int i = tid; i < 735; i += 256) xin[i] = xo[b * 735 + i];
  int co = tid & 31;
  float wreg[8];
#pragma unroll
  for (int k = 0; k < 8; k++) wreg[k] = k1[co * 8 + k];
  float bs = kb1[co];
  __syncthreads();
  for (int idx = tid; idx < 242 * 32; idx += 256) {
    int l = idx >> 5;  // co == idx&31 == tid&31
    int base = l * 3;
    float a0 = bs, a1 = bs, a2 = bs;
#pragma unroll
    for (int k = 0; k < 8; k++) {
      float wv = wreg[k];
      a0 += wv * xin[base + k];
      a1 += wv * xin[base + 1 + k];
      a2 += wv * xin[base + 2 + k];
    }
    out[(size_t)b * (242 * 32) + idx] =
        __float2bfloat16(fmaxf(0.f, fmaxf(a0, fmaxf(a1, a2))));
  }
}

// ======================= MFMA implicit-GEMM conv + bias + relu + pool3 ==============
// in: [B, LIN, CI] bf16 (pos-major). out: [B, LOUT, NCO] bf16.
// Each block: G graphs, 64 out-channels (4 waves x 16). K = 8*CI.
template <int CI, int LIN, int LPAD, int MT, int LOUT, int G, int NCO>
__global__ __launch_bounds__(256) void convmfma_kernel(const bf16* __restrict__ in,
                                                       const bf16* __restrict__ Wr,
                                                       const float* __restrict__ kb,
                                                       bf16* __restrict__ outp) {
  constexpr int KSTEPS = 8 * CI / 32;
  constexpr int CIP = CI + 8;  // pad to break power-of-2 LDS row stride
  __shared__ __align__(16) bf16 lds_in[G * LPAD * CIP];
  __shared__ bf16 stg[4][MT * 16][16];
  int tid = threadIdx.x;
  int w = tid >> 6, lane = tid & 63;
  int quad = lane >> 4, l16 = lane & 15;
  int bg = blockIdx.x;
  int co0 = blockIdx.y * 64 + w * 16;

  // B (weight) fragments in registers: B[k=quad*8+j][n=l16] per k-step
  short8 bfrag[KSTEPS];
#pragma unroll
  for (int s = 0; s < KSTEPS; s++) {
#pragma unroll
    for (int j = 0; j < 8; j++) {
      int k = s * 32 + quad * 8 + j;
      bfrag[s][j] = ((const short*)Wr)[k * NCO + co0 + l16];
    }
  }

  // stage G inputs into LDS (row-padded CI -> CIP)
  const bf16* gin = in + (size_t)bg * G * LIN * CI;
  constexpr int NELEM = G * LIN * CI;
  for (int i = tid; i < NELEM / 8; i += 256) {
    int flat = i * 8;
    int g = flat / (LIN * CI);
    int rem = flat - g * (LIN * CI);
    int row = rem / CI, ci = rem - row * CI;
    *(short8*)&lds_in[(g * LPAD + row) * CIP + ci] = *(const short8*)&gin[flat];
  }
  constexpr int PADE = G * (LPAD - LIN) * CIP;
  for (int i = tid; i < PADE / 8; i += 256) {
    int flat = i * 8;
    int g = flat / ((LPAD - LIN) * CIP);
    int rem = flat - g * ((LPAD - LIN) * CIP);
    short8 z = {0, 0, 0, 0, 0, 0, 0, 0};
    *(short8*)&lds_in[(g * LPAD + LIN) * CIP + rem] = z;
  }
  __syncthreads();

  for (int g = 0; g < G; g++) {
    const bf16* base = &lds_in[g * LPAD * CIP];
#pragma unroll
    for (int mt = 0; mt < MT; mt++) {
      floatx4 acc = {0.f, 0.f, 0.f, 0.f};
      int m = mt * 16 + l16;
#pragma unroll
      for (int s = 0; s < KSTEPS; s++) {
        int kg0 = s * 32 + quad * 8;
        int dl = kg0 / CI;
        int ci0 = kg0 % CI;
        short8 a = *(const short8*)&base[(m + dl) * CIP + ci0];
        acc = __builtin_amdgcn_mfma_f32_16x16x32_bf16(a, bfrag[s], acc, 0, 0, 0);
      }
#pragma unroll
      for (int r = 0; r < 4; r++)
        stg[w][mt * 16 + quad * 4 + r][l16] = __float2bfloat16(acc[r]);
    }
    __syncthreads();
    float bias = kb[co0 + l16];
    for (int it = lane; it < LOUT * 16; it += 64) {
      int l = it >> 4;
      float v0 = __bfloat162float(stg[w][3 * l][l16]);
      float v1 = __bfloat162float(stg[w][3 * l + 1][l16]);
      float v2 = __bfloat162float(stg[w][3 * l + 2][l16]);
      float v = fmaxf(fmaxf(v0, v1), v2) + bias;
      outp[((size_t)(bg * G + g) * LOUT + l) * NCO + co0 + l16] =
          __float2bfloat16(fmaxf(v, 0.f));
    }
    __syncthreads();
  }
}

// ======================= final head =======================
__global__ __launch_bounds__(256) void final_kernel(const float* __restrict__ f2,
                                                    const float* __restrict__ Wo,
                                                    const float* __restrict__ bo,
                                                    float* __restrict__ out) {
  int wid = (blockIdx.x * blockDim.x + threadIdx.x) >> 6;
  int lane = threadIdx.x & 63;
  if (wid >= NB) return;
  float s = f2[wid * 128 + lane] * Wo[lane] + f2[wid * 128 + 64 + lane] * Wo[64 + lane];
  for (int o = 32; o > 0; o >>= 1) s += __shfl_down(s, o);
  if (lane == 0) out[wid] = s + bo[0];
}

// ======================= launch =======================
extern "C" void kernel_launch(void* const* d_in, const int* in_sizes, int n_in,
                              void* d_out, int out_size, void* d_ws, size_t ws_size,
                              hipStream_t stream) {
  const float* x   = (const float*)d_in[0];
  const int*   ei  = (const int*)d_in[1];
  const float* xo  = (const float*)d_in[3];
  const float* W1  = (const float*)d_in[4];  const float* b1  = (const float*)d_in[5];
  const float* W2  = (const float*)d_in[6];  const float* b2  = (const float*)d_in[7];
  const float* W3  = (const float*)d_in[8];  const float* b3  = (const float*)d_in[9];
  const float* Wg1 = (const float*)d_in[10]; const float* bg1 = (const float*)d_in[11];
  const float* Wg2 = (const float*)d_in[12]; const float* bg2 = (const float*)d_in[13];
  const float* k1  = (const float*)d_in[14]; const float* kb1 = (const float*)d_in[15];
  const float* k2  = (const float*)d_in[16]; const float* kb2 = (const float*)d_in[17];
  const float* k3  = (const float*)d_in[18]; const float* kb3 = (const float*)d_in[19];
  const float* Wxt = (const float*)d_in[20]; const float* bxt = (const float*)d_in[21];
  const float* Wf1 = (const float*)d_in[22]; const float* bf1 = (const float*)d_in[23];
  const float* Wf2 = (const float*)d_in[24]; const float* bf2 = (const float*)d_in[25];
  const float* Wo  = (const float*)d_in[26]; const float* bo  = (const float*)d_in[27];
  float* out = (float*)d_out;

  char* ws = (char*)d_ws;
  size_t off = 0;
  auto alloc = [&](size_t bytes) -> void* {
    void* p = ws + off;
    off += (bytes + 255) & ~(size_t)255;
    return p;
  };

  int*   indeg   = (int*)alloc((size_t)N_NODES * 4);
  float* dinv    = (float*)alloc((size_t)N_NODES * 4);
  int*   rowstart= (int*)alloc((size_t)(N_NODES + 1) * 4);
  int*   cursor  = (int*)alloc((size_t)N_NODES * 4);
  int*   bsums   = (int*)alloc(640 * 4);
  int*   boffs   = (int*)alloc(640 * 4);
  int*   csr     = (int*)alloc((size_t)N_EDGES * 4);                    // 10.5 MB
  bf16*  nb1     = (bf16*)alloc((size_t)N_NODES * 156 * 2);             // 51.1 MB
  bf16*  nb2     = (bf16*)alloc((size_t)NB * 32 * 242 * 2);             // 63.4 MB
  float* g       = (float*)alloc((size_t)NB * 312 * 4);
  float* g1f1    = (float*)alloc((size_t)NB * 1024 * 4);
  float* gt      = (float*)alloc((size_t)NB * 256 * 4);
  float* f2      = (float*)alloc((size_t)NB * 128 * 4);
  bf16*  Wr2     = (bf16*)alloc((size_t)256 * 64 * 2);                  // conv2 weights
  bf16*  Wr3     = (bf16*)alloc((size_t)512 * 128 * 2);                 // conv3 weights
  float* Wp      = (float*)alloc((size_t)2944 * 128 * 4);               // permuted Wxt

  bf16* xb = nb2;                 // [N,78]
  bf16* h  = nb2;                 // h1 [N,78], h2 [N,156]
  bf16* ag = nb1;                 // agg buffers
  bf16* c1 = nb2;                 // [B,242,32] pos-major
  bf16* c2 = nb1;                 // [B,78,64]  pos-major
  bf16* c3 = nb2;                 // [B,23,128] = [B,2944] flat

  // ---- weight prep (independent; every call) ----
  wprep_kernel<32, 64><<<(8 * 32 * 64 + 255) / 256, 256, 0, stream>>>(k2, Wr2);
  wprep_kernel<64, 128><<<(8 * 64 * 128 + 255) / 256, 256, 0, stream>>>(k3, Wr3);
  wxtprep_kernel<<<(2944 * 128 + 255) / 256, 256, 0, stream>>>(Wxt, Wp);

  // ---- CSR build + degree norm ----
  zero_kernel<<<N_NODES / 256, 256, 0, stream>>>(indeg);
  count_kernel<<<N_EDGES / 256, 256, 0, stream>>>(ei, indeg);
  dinv_kernel<<<N_NODES / 256, 256, 0, stream>>>(indeg, dinv);
  scan1_kernel<<<640, 256, 0, stream>>>(indeg, rowstart, bsums);
  scan2_kernel<<<1, 64, 0, stream>>>(bsums, boffs, rowstart);
  scan3_kernel<<<640, 256, 0, stream>>>(rowstart, cursor, boffs);
  scatter_kernel<<<N_EDGES / 256, 256, 0, stream>>>(ei, cursor, csr);

  // ---- GCN layers (aggregate-first: relu(agg(h) @ W + b)) ----
  cast_kernel<<<N_NODES * 78 / 256, 256, 0, stream>>>(x, xb);
  agg_kernel<2><<<N_NODES / 4, 256, 0, stream>>>(xb, dinv, rowstart, csr, ag, 78);
  sgemm_kernel<bf16, bf16><<<dim3(2, N_NODES / 64), 256, 0, stream>>>(
      ag, W1, b1, h, N_NODES, 78, 78, 78, 0, 1);
  agg_kernel<2><<<N_NODES / 4, 256, 0, stream>>>(h, dinv, rowstart, csr, ag, 78);
  sgemm_kernel<bf16, bf16><<<dim3(3, N_NODES / 64), 256, 0, stream>>>(
      ag, W2, b2, h, N_NODES, 156, 78, 156, 0, 1);
  agg_kernel<3><<<N_NODES / 4, 256, 0, stream>>>(h, dinv, rowstart, csr, ag, 156);
  gcn3_segmax_kernel<<<NB, 320, 0, stream>>>(ag, W3, b3, g);

  // ---- graph head ----
  sgemm_kernel<float, float><<<dim3(16, NB / 64), 256, 0, stream>>>(
      g, Wg1, bg1, g1f1, NB, 1024, 312, 1024, 0, 1);
  sgemm_kernel<float, float><<<dim3(2, NB / 64), 256, 0, stream>>>(
      g1f1, Wg2, bg2, gt, NB, 128, 1024, 256, 0, 0);

  // ---- conv tower (pos-major, MFMA) ----
  conv1_kernel<<<NB, 256, 0, stream>>>(xo, k1, kb1, c1);
  // conv2: CI=32, LIN=242, LPAD=248, MT=15 (M=235 pre-pool), LOUT=78, G=2, NCO=64
  convmfma_kernel<32, 242, 248, 15, 78, 2, 64>
      <<<dim3(NB / 2, 1), 256, 0, stream>>>(c1, Wr2, kb2, c2);
  // conv3: CI=64, LIN=78, LPAD=88, MT=5 (M=71 pre-pool), LOUT=23, G=4, NCO=128
  convmfma_kernel<64, 78, 88, 5, 23, 4, 128>
      <<<dim3(NB / 4, 2), 256, 0, stream>>>(c2, Wr3, kb3, c3);
  sgemm_kernel<bf16, float><<<dim3(2, NB / 64), 256, 0, stream>>>(
      c3, Wp, bxt, gt, NB, 128, 2944, 256, 128, 0);

  // ---- fused head ----
  sgemm_kernel<float, float><<<dim3(16, NB / 64), 256, 0, stream>>>(
      gt, Wf1, bf1, g1f1, NB, 1024, 256, 1024, 0, 1);
  sgemm_kernel<float, float><<<dim3(2, NB / 64), 256, 0, stream>>>(
      g1f1, Wf2, bf2, f2, NB, 128, 1024, 128, 0, 1);
  final_kernel<<<NB * 64 / 256, 256, 0, stream>>>(f2, Wo, bo, out);
}

// Round 4
// 3053.355 us; speedup vs baseline: 2.0328x; 1.1389x over previous
//
#include <hip/hip_runtime.h>
#include <hip/hip_bf16.h>

#define N_NODES 163840
#define N_EDGES 2621440
#define NB      4096

typedef __hip_bfloat16 bf16;
typedef __attribute__((ext_vector_type(8))) short short8;
typedef __attribute__((ext_vector_type(4))) float floatx4;

__device__ inline float tofloat(float v) { return v; }
__device__ inline float tofloat(bf16 v) { return __bfloat162float(v); }
__device__ inline void storev(float* p, float v) { *p = v; }
__device__ inline void storev(bf16* p, float v) { *p = __float2bfloat16(v); }

// ======================= graph preprocessing =======================

__global__ __launch_bounds__(256) void zero_kernel(int* __restrict__ p) {
  p[blockIdx.x * 256 + threadIdx.x] = 0;
}

__global__ __launch_bounds__(256) void count_kernel(const int* __restrict__ ei,
                                                    int* __restrict__ indeg) {
  int e = blockIdx.x * 256 + threadIdx.x;
  if (e < N_EDGES) atomicAdd(&indeg[ei[N_EDGES + e]], 1);
}

__global__ __launch_bounds__(256) void dinv_kernel(const int* __restrict__ indeg,
                                                   float* __restrict__ dinv) {
  int i = blockIdx.x * 256 + threadIdx.x;
  if (i < N_NODES) dinv[i] = rsqrtf((float)indeg[i] + 1.0f);
}

__global__ __launch_bounds__(256) void scan1_kernel(const int* __restrict__ indeg,
                                                    int* __restrict__ rowstart,
                                                    int* __restrict__ bsums) {
  __shared__ int s[256];
  int tid = threadIdx.x;
  int i = blockIdx.x * 256 + tid;
  int v = indeg[i];
  s[tid] = v;
  __syncthreads();
  for (int off = 1; off < 256; off <<= 1) {
    int x = (tid >= off) ? s[tid - off] : 0;
    __syncthreads();
    s[tid] += x;
    __syncthreads();
  }
  rowstart[i] = s[tid] - v;  // exclusive within block
  if (tid == 255) bsums[blockIdx.x] = s[255];
}

__global__ void scan2_kernel(const int* __restrict__ bsums, int* __restrict__ boffs,
                             int* __restrict__ rowstart) {
  if (threadIdx.x == 0 && blockIdx.x == 0) {
    int run = 0;
    for (int i = 0; i < 640; i++) { boffs[i] = run; run += bsums[i]; }
    rowstart[N_NODES] = run;  // == N_EDGES
  }
}

__global__ __launch_bounds__(256) void scan3_kernel(int* __restrict__ rowstart,
                                                    int* __restrict__ cursor,
                                                    const int* __restrict__ boffs) {
  int i = blockIdx.x * 256 + threadIdx.x;
  int v = rowstart[i] + boffs[blockIdx.x];
  rowstart[i] = v;
  cursor[i] = v;
}

__global__ __launch_bounds__(256) void scatter_kernel(const int* __restrict__ ei,
                                                      int* __restrict__ cursor,
                                                      int* __restrict__ csr_src) {
  int e = blockIdx.x * 256 + threadIdx.x;
  if (e < N_EDGES) {
    int s = ei[e], d = ei[N_EDGES + e];
    int pos = atomicAdd(&cursor[d], 1);
    csr_src[pos] = s;
  }
}

// xb[n,f] = x[n,f] * dinv[n]  (pre-scaled features; see agg_kernel)
__global__ __launch_bounds__(256) void cast_scale_kernel(const float* __restrict__ x,
                                                         const float* __restrict__ dinv,
                                                         bf16* __restrict__ xb) {
  int i = blockIdx.x * 256 + threadIdx.x;
  xb[i] = __float2bfloat16(x[i] * dinv[i / 78]);
}

// ======================= GCN aggregation =======================
// Inputs pre-scaled: hs[n] = h[n] * dinv[n].
// out[n,f] = dn * ( sum_{e:dst=n} hs[src_e,f] + hs[n,f] )
// one wave per node, features across lanes; edge loop unrolled x4 for MLP.
template <int NR>
__global__ __launch_bounds__(256) void agg_kernel(const bf16* __restrict__ hs,
                                                  const float* __restrict__ dinv,
                                                  const int* __restrict__ rowstart,
                                                  const int* __restrict__ csr,
                                                  bf16* __restrict__ out, int F) {
  int node = blockIdx.x * 4 + (threadIdx.x >> 6);
  int lane = threadIdx.x & 63;
  float acc[NR];
#pragma unroll
  for (int r = 0; r < NR; r++) acc[r] = 0.f;
  int st = rowstart[node], en = rowstart[node + 1];
  float dn = dinv[node];
  int e = st;
  for (; e + 4 <= en; e += 4) {
    int s0 = csr[e], s1 = csr[e + 1], s2 = csr[e + 2], s3 = csr[e + 3];
    const bf16* r0 = hs + (size_t)s0 * F;
    const bf16* r1 = hs + (size_t)s1 * F;
    const bf16* r2 = hs + (size_t)s2 * F;
    const bf16* r3 = hs + (size_t)s3 * F;
    float v0[NR], v1[NR], v2[NR], v3[NR];
#pragma unroll
    for (int r = 0; r < NR; r++) {
      int f = lane + 64 * r;
      bool ok = f < F;
      v0[r] = ok ? tofloat(r0[f]) : 0.f;
      v1[r] = ok ? tofloat(r1[f]) : 0.f;
      v2[r] = ok ? tofloat(r2[f]) : 0.f;
      v3[r] = ok ? tofloat(r3[f]) : 0.f;
    }
#pragma unroll
    for (int r = 0; r < NR; r++) acc[r] += (v0[r] + v1[r]) + (v2[r] + v3[r]);
  }
  for (; e < en; e++) {
    int s = csr[e];
    const bf16* hr = hs + (size_t)s * F;
#pragma unroll
    for (int r = 0; r < NR; r++) {
      int f = lane + 64 * r;
      if (f < F) acc[r] += tofloat(hr[f]);
    }
  }
  const bf16* hn = hs + (size_t)node * F;
  bf16* on = out + (size_t)node * F;
#pragma unroll
  for (int r = 0; r < NR; r++) {
    int f = lane + 64 * r;
    if (f < F) {
      float v = dn * (acc[r] + tofloat(hn[f]));
      on[f] = __float2bfloat16(v);
    }
  }
}

// ======================= generic SGEMM (A: TA, B: f32, C: TC) =======================
// C[row, coff+col] = act(A @ B + bias) * (rowScale ? rowScale[row] : 1)
template <typename TA, typename TC>
__global__ __launch_bounds__(256) void sgemm_kernel(const TA* __restrict__ A,
                                                    const float* __restrict__ Bm,
                                                    const float* __restrict__ bias,
                                                    const float* __restrict__ rowScale,
                                                    TC* __restrict__ C, int M, int Nc,
                                                    int K, int ldc, int coff, int doRelu) {
  __shared__ float As[16][65];
  __shared__ float Bs[16][65];
  int tid = threadIdx.x;
  int tx = tid & 15, ty = tid >> 4;
  int rowBase = blockIdx.y * 64;
  int colBase = blockIdx.x * 64;
  float acc[4][4] = {};
  for (int k0 = 0; k0 < K; k0 += 16) {
    {
      int kk = tid & 15;
      int r0 = tid >> 4;
#pragma unroll
      for (int j = 0; j < 4; j++) {
        int r = r0 + 16 * j;
        int grow = rowBase + r, gk = k0 + kk;
        As[kk][r] = (grow < M && gk < K) ? tofloat(A[(size_t)grow * K + gk]) : 0.f;
      }
      int c = tid & 63;
      int kk2 = tid >> 6;
#pragma unroll
      for (int j = 0; j < 4; j++) {
        int k = kk2 + 4 * j;
        int gcol = colBase + c, gk = k0 + k;
        Bs[k][c] = (gk < K && gcol < Nc) ? Bm[(size_t)gk * Nc + gcol] : 0.f;
      }
    }
    __syncthreads();
#pragma unroll
    for (int kk = 0; kk < 16; kk++) {
      float ar[4], br[4];
#pragma unroll
      for (int i = 0; i < 4; i++) ar[i] = As[kk][ty * 4 + i];
#pragma unroll
      for (int j = 0; j < 4; j++) br[j] = Bs[kk][tx * 4 + j];
#pragma unroll
      for (int i = 0; i < 4; i++)
#pragma unroll
        for (int j = 0; j < 4; j++) acc[i][j] += ar[i] * br[j];
    }
    __syncthreads();
  }
#pragma unroll
  for (int i = 0; i < 4; i++) {
    int row = rowBase + ty * 4 + i;
    if (row >= M) continue;
    float rs = rowScale ? rowScale[row] : 1.f;
#pragma unroll
    for (int j = 0; j < 4; j++) {
      int col = colBase + tx * 4 + j;
      if (col >= Nc) continue;
      float v = acc[i][j];
      if (bias) v += bias[col];
      if (doRelu) v = fmaxf(v, 0.f);
      v *= rs;
      storev(&C[(size_t)row * ldc + coff + col], v);
    }
  }
}

// ======= fused layer-3 GCN transform + bias + relu + segment-max (40 nodes/graph) ====
__global__ __launch_bounds__(320) void gcn3_segmax_kernel(const bf16* __restrict__ agg2,
                                                          const float* __restrict__ W3,
                                                          const float* __restrict__ b3,
                                                          float* __restrict__ g) {
  __shared__ float a[40][156];
  int gb = blockIdx.x, tid = threadIdx.x;
  for (int i = tid; i < 40 * 156; i += 320)
    a[i / 156][i % 156] = tofloat(agg2[(size_t)gb * (40 * 156) + i]);
  __syncthreads();
  if (tid < 312) {
    float acc[40];
#pragma unroll
    for (int n = 0; n < 40; n++) acc[n] = 0.f;
    for (int k = 0; k < 156; k += 4) {
      float w0 = W3[(size_t)k * 312 + tid];
      float w1 = W3[(size_t)(k + 1) * 312 + tid];
      float w2 = W3[(size_t)(k + 2) * 312 + tid];
      float w3 = W3[(size_t)(k + 3) * 312 + tid];
#pragma unroll
      for (int n = 0; n < 40; n++) {
        float4 av = *(const float4*)&a[n][k];
        acc[n] += av.x * w0 + av.y * w1 + av.z * w2 + av.w * w3;
      }
    }
    float m = acc[0];
#pragma unroll
    for (int n = 1; n < 40; n++) m = fmaxf(m, acc[n]);
    g[gb * 312 + tid] = fmaxf(m + b3[tid], 0.f);
  }
}

// ======================= weight prep for MFMA convs =======================
template <int CI, int NCO>
__global__ __launch_bounds__(256) void wprep_kernel(const float* __restrict__ kw,
                                                    bf16* __restrict__ Wr) {
  int idx = blockIdx.x * 256 + threadIdx.x;
  if (idx < 8 * CI * NCO) {
    int co = idx % NCO, k = idx / NCO;
    int dl = k / CI, ci = k % CI;
    Wr[idx] = __float2bfloat16(kw[(co * CI + ci) * 8 + dl]);
  }
}

__global__ __launch_bounds__(256) void wxtprep_kernel(const float* __restrict__ Wxt,
                                                      float* __restrict__ Wp) {
  int idx = blockIdx.x * 256 + threadIdx.x;
  if (idx < 2944 * 128) {
    int o = idx & 127, r = idx >> 7;
    int l = r >> 7, co = r & 127;
    Wp[idx] = Wxt[((size_t)(co * 23 + l)) * 128 + o];
  }
}

// ======================= conv1: [B,735] f32 -> [B,242,32] bf16 (pos-major) =========
__global__ __launch_bounds__(256) void conv1_kernel(const float* __restrict__ xo,
                                                    const float* __restrict__ k1,
                                                    const float* __restrict__ kb1,
                                                    bf16* __restrict__ out) {
  __shared__ float xin[735];
  int b = blockIdx.x, tid = threadIdx.x;
  for (int i = tid; i < 735; i += 256) xin[i] = xo[b * 735 + i];
  int co = tid & 31;
  float wreg[8];
#pragma unroll
  for (int k = 0; k < 8; k++) wreg[k] = k1[co * 8 + k];
  float bs = kb1[co];
  __syncthreads();
  for (int idx = tid; idx < 242 * 32; idx += 256) {
    int l = idx >> 5;
    int base = l * 3;
    float a0 = bs, a1 = bs, a2 = bs;
#pragma unroll
    for (int k = 0; k < 8; k++) {
      float wv = wreg[k];
      a0 += wv * xin[base + k];
      a1 += wv * xin[base + 1 + k];
      a2 += wv * xin[base + 2 + k];
    }
    out[(size_t)b * (242 * 32) + idx] =
        __float2bfloat16(fmaxf(0.f, fmaxf(a0, fmaxf(a1, a2))));
  }
}

// ======================= MFMA implicit-GEMM conv + bias + relu + pool3 ==============
template <int CI, int LIN, int LPAD, int MT, int LOUT, int G, int NCO>
__global__ __launch_bounds__(256) void convmfma_kernel(const bf16* __restrict__ in,
                                                       const bf16* __restrict__ Wr,
                                                       const float* __restrict__ kb,
                                                       bf16* __restrict__ outp) {
  constexpr int KSTEPS = 8 * CI / 32;
  constexpr int CIP = CI + 8;
  __shared__ __align__(16) bf16 lds_in[G * LPAD * CIP];
  __shared__ bf16 stg[4][MT * 16][16];
  int tid = threadIdx.x;
  int w = tid >> 6, lane = tid & 63;
  int quad = lane >> 4, l16 = lane & 15;
  int bg = blockIdx.x;
  int co0 = blockIdx.y * 64 + w * 16;

  short8 bfrag[KSTEPS];
#pragma unroll
  for (int s = 0; s < KSTEPS; s++) {
#pragma unroll
    for (int j = 0; j < 8; j++) {
      int k = s * 32 + quad * 8 + j;
      bfrag[s][j] = ((const short*)Wr)[k * NCO + co0 + l16];
    }
  }

  const bf16* gin = in + (size_t)bg * G * LIN * CI;
  constexpr int NELEM = G * LIN * CI;
  for (int i = tid; i < NELEM / 8; i += 256) {
    int flat = i * 8;
    int g = flat / (LIN * CI);
    int rem = flat - g * (LIN * CI);
    int row = rem / CI, ci = rem - row * CI;
    *(short8*)&lds_in[(g * LPAD + row) * CIP + ci] = *(const short8*)&gin[flat];
  }
  constexpr int PADE = G * (LPAD - LIN) * CIP;
  for (int i = tid; i < PADE / 8; i += 256) {
    int flat = i * 8;
    int g = flat / ((LPAD - LIN) * CIP);
    int rem = flat - g * ((LPAD - LIN) * CIP);
    short8 z = {0, 0, 0, 0, 0, 0, 0, 0};
    *(short8*)&lds_in[(g * LPAD + LIN) * CIP + rem] = z;
  }
  __syncthreads();

  for (int g = 0; g < G; g++) {
    const bf16* base = &lds_in[g * LPAD * CIP];
#pragma unroll
    for (int mt = 0; mt < MT; mt++) {
      floatx4 acc = {0.f, 0.f, 0.f, 0.f};
      int m = mt * 16 + l16;
#pragma unroll
      for (int s = 0; s < KSTEPS; s++) {
        int kg0 = s * 32 + quad * 8;
        int dl = kg0 / CI;
        int ci0 = kg0 % CI;
        short8 a = *(const short8*)&base[(m + dl) * CIP + ci0];
        acc = __builtin_amdgcn_mfma_f32_16x16x32_bf16(a, bfrag[s], acc, 0, 0, 0);
      }
#pragma unroll
      for (int r = 0; r < 4; r++)
        stg[w][mt * 16 + quad * 4 + r][l16] = __float2bfloat16(acc[r]);
    }
    __syncthreads();
    float bias = kb[co0 + l16];
    for (int it = lane; it < LOUT * 16; it += 64) {
      int l = it >> 4;
      float v0 = __bfloat162float(stg[w][3 * l][l16]);
      float v1 = __bfloat162float(stg[w][3 * l + 1][l16]);
      float v2 = __bfloat162float(stg[w][3 * l + 2][l16]);
      float v = fmaxf(fmaxf(v0, v1), v2) + bias;
      outp[((size_t)(bg * G + g) * LOUT + l) * NCO + co0 + l16] =
          __float2bfloat16(fmaxf(v, 0.f));
    }
    __syncthreads();
  }
}

// ======================= final head =======================
__global__ __launch_bounds__(256) void final_kernel(const float* __restrict__ f2,
                                                    const float* __restrict__ Wo,
                                                    const float* __restrict__ bo,
                                                    float* __restrict__ out) {
  int wid = (blockIdx.x * blockDim.x + threadIdx.x) >> 6;
  int lane = threadIdx.x & 63;
  if (wid >= NB) return;
  float s = f2[wid * 128 + lane] * Wo[lane] + f2[wid * 128 + 64 + lane] * Wo[64 + lane];
  for (int o = 32; o > 0; o >>= 1) s += __shfl_down(s, o);
  if (lane == 0) out[wid] = s + bo[0];
}

// ======================= launch =======================
extern "C" void kernel_launch(void* const* d_in, const int* in_sizes, int n_in,
                              void* d_out, int out_size, void* d_ws, size_t ws_size,
                              hipStream_t stream) {
  const float* x   = (const float*)d_in[0];
  const int*   ei  = (const int*)d_in[1];
  const float* xo  = (const float*)d_in[3];
  const float* W1  = (const float*)d_in[4];  const float* b1  = (const float*)d_in[5];
  const float* W2  = (const float*)d_in[6];  const float* b2  = (const float*)d_in[7];
  const float* W3  = (const float*)d_in[8];  const float* b3  = (const float*)d_in[9];
  const float* Wg1 = (const float*)d_in[10]; const float* bg1 = (const float*)d_in[11];
  const float* Wg2 = (const float*)d_in[12]; const float* bg2 = (const float*)d_in[13];
  const float* k1  = (const float*)d_in[14]; const float* kb1 = (const float*)d_in[15];
  const float* k2  = (const float*)d_in[16]; const float* kb2 = (const float*)d_in[17];
  const float* k3  = (const float*)d_in[18]; const float* kb3 = (const float*)d_in[19];
  const float* Wxt = (const float*)d_in[20]; const float* bxt = (const float*)d_in[21];
  const float* Wf1 = (const float*)d_in[22]; const float* bf1 = (const float*)d_in[23];
  const float* Wf2 = (const float*)d_in[24]; const float* bf2 = (const float*)d_in[25];
  const float* Wo  = (const float*)d_in[26]; const float* bo  = (const float*)d_in[27];
  float* out = (float*)d_out;

  char* ws = (char*)d_ws;
  size_t off = 0;
  auto alloc = [&](size_t bytes) -> void* {
    void* p = ws + off;
    off += (bytes + 255) & ~(size_t)255;
    return p;
  };

  int*   indeg   = (int*)alloc((size_t)N_NODES * 4);
  float* dinv    = (float*)alloc((size_t)N_NODES * 4);
  int*   rowstart= (int*)alloc((size_t)(N_NODES + 1) * 4);
  int*   cursor  = (int*)alloc((size_t)N_NODES * 4);
  int*   bsums   = (int*)alloc(640 * 4);
  int*   boffs   = (int*)alloc(640 * 4);
  int*   csr     = (int*)alloc((size_t)N_EDGES * 4);
  bf16*  nb1     = (bf16*)alloc((size_t)N_NODES * 156 * 2);
  bf16*  nb2     = (bf16*)alloc((size_t)NB * 32 * 242 * 2);
  float* g       = (float*)alloc((size_t)NB * 312 * 4);
  float* g1f1    = (float*)alloc((size_t)NB * 1024 * 4);
  float* gt      = (float*)alloc((size_t)NB * 256 * 4);
  float* f2      = (float*)alloc((size_t)NB * 128 * 4);
  bf16*  Wr2     = (bf16*)alloc((size_t)256 * 64 * 2);
  bf16*  Wr3     = (bf16*)alloc((size_t)512 * 128 * 2);
  float* Wp      = (float*)alloc((size_t)2944 * 128 * 4);

  bf16* xb = nb2;                 // [N,78] pre-scaled
  bf16* h  = nb2;                 // h1s [N,78], h2s [N,156] (pre-scaled)
  bf16* ag = nb1;                 // agg buffers
  bf16* c1 = nb2;                 // [B,242,32] pos-major
  bf16* c2 = nb1;                 // [B,78,64]  pos-major
  bf16* c3 = nb2;                 // [B,23,128] = [B,2944] flat

  // ---- weight prep ----
  wprep_kernel<32, 64><<<(8 * 32 * 64 + 255) / 256, 256, 0, stream>>>(k2, Wr2);
  wprep_kernel<64, 128><<<(8 * 64 * 128 + 255) / 256, 256, 0, stream>>>(k3, Wr3);
  wxtprep_kernel<<<(2944 * 128 + 255) / 256, 256, 0, stream>>>(Wxt, Wp);

  // ---- CSR build + degree norm ----
  zero_kernel<<<N_NODES / 256, 256, 0, stream>>>(indeg);
  count_kernel<<<N_EDGES / 256, 256, 0, stream>>>(ei, indeg);
  dinv_kernel<<<N_NODES / 256, 256, 0, stream>>>(indeg, dinv);
  scan1_kernel<<<640, 256, 0, stream>>>(indeg, rowstart, bsums);
  scan2_kernel<<<1, 64, 0, stream>>>(bsums, boffs, rowstart);
  scan3_kernel<<<640, 256, 0, stream>>>(rowstart, cursor, boffs);
  scatter_kernel<<<N_EDGES / 256, 256, 0, stream>>>(ei, cursor, csr);

  // ---- GCN layers (aggregate-first, dinv folded into stored features) ----
  cast_scale_kernel<<<N_NODES * 78 / 256, 256, 0, stream>>>(x, dinv, xb);
  agg_kernel<2><<<N_NODES / 4, 256, 0, stream>>>(xb, dinv, rowstart, csr, ag, 78);
  sgemm_kernel<bf16, bf16><<<dim3(2, N_NODES / 64), 256, 0, stream>>>(
      ag, W1, b1, dinv, h, N_NODES, 78, 78, 78, 0, 1);
  agg_kernel<2><<<N_NODES / 4, 256, 0, stream>>>(h, dinv, rowstart, csr, ag, 78);
  sgemm_kernel<bf16, bf16><<<dim3(3, N_NODES / 64), 256, 0, stream>>>(
      ag, W2, b2, dinv, h, N_NODES, 156, 78, 156, 0, 1);
  agg_kernel<3><<<N_NODES / 4, 256, 0, stream>>>(h, dinv, rowstart, csr, ag, 156);
  gcn3_segmax_kernel<<<NB, 320, 0, stream>>>(ag, W3, b3, g);

  // ---- graph head ----
  sgemm_kernel<float, float><<<dim3(16, NB / 64), 256, 0, stream>>>(
      g, Wg1, bg1, nullptr, g1f1, NB, 1024, 312, 1024, 0, 1);
  sgemm_kernel<float, float><<<dim3(2, NB / 64), 256, 0, stream>>>(
      g1f1, Wg2, bg2, nullptr, gt, NB, 128, 1024, 256, 0, 0);

  // ---- conv tower (pos-major, MFMA) ----
  conv1_kernel<<<NB, 256, 0, stream>>>(xo, k1, kb1, c1);
  convmfma_kernel<32, 242, 248, 15, 78, 2, 64>
      <<<dim3(NB / 2, 1), 256, 0, stream>>>(c1, Wr2, kb2, c2);
  convmfma_kernel<64, 78, 88, 5, 23, 4, 128>
      <<<dim3(NB / 4, 2), 256, 0, stream>>>(c2, Wr3, kb3, c3);
  sgemm_kernel<bf16, float><<<dim3(2, NB / 64), 256, 0, stream>>>(
      c3, Wp, bxt, nullptr, gt, NB, 128, 2944, 256, 128, 0);

  // ---- fused head ----
  sgemm_kernel<float, float><<<dim3(16, NB / 64), 256, 0, stream>>>(
      gt, Wf1, bf1, nullptr, g1f1, NB, 1024, 256, 1024, 0, 1);
  sgemm_kernel<float, float><<<dim3(2, NB / 64), 256, 0, stream>>>(
      g1f1, Wf2, bf2, nullptr, f2, NB, 128, 1024, 128, 0, 1);
  final_kernel<<<NB * 64 / 256, 256, 0, stream>>>(f2, Wo, bo, out);
}

// Round 5
// 2122.042 us; speedup vs baseline: 2.9250x; 1.4389x over previous
//
#include <hip/hip_runtime.h>
#include <hip/hip_bf16.h>

#define N_NODES 163840
#define N_EDGES 2621440
#define NB      4096

typedef __hip_bfloat16 bf16;
typedef __attribute__((ext_vector_type(8))) short short8;
typedef __attribute__((ext_vector_type(4))) float floatx4;

__device__ inline float tofloat(float v) { return v; }
__device__ inline float tofloat(bf16 v) { return __bfloat162float(v); }
__device__ inline void storev(float* p, float v) { *p = v; }
__device__ inline void storev(bf16* p, float v) { *p = __float2bfloat16(v); }

// ======================= graph preprocessing =======================

__global__ __launch_bounds__(256) void zero_kernel(int* __restrict__ p) {
  p[blockIdx.x * 256 + threadIdx.x] = 0;
}

__global__ __launch_bounds__(256) void count_kernel(const int* __restrict__ ei,
                                                    int* __restrict__ indeg) {
  int e = blockIdx.x * 256 + threadIdx.x;
  if (e < N_EDGES) atomicAdd(&indeg[ei[N_EDGES + e]], 1);
}

__global__ __launch_bounds__(256) void dinv_kernel(const int* __restrict__ indeg,
                                                   float* __restrict__ dinv) {
  int i = blockIdx.x * 256 + threadIdx.x;
  if (i < N_NODES) dinv[i] = rsqrtf((float)indeg[i] + 1.0f);
}

__global__ __launch_bounds__(256) void scan1_kernel(const int* __restrict__ indeg,
                                                    int* __restrict__ rowstart,
                                                    int* __restrict__ bsums) {
  __shared__ int s[256];
  int tid = threadIdx.x;
  int i = blockIdx.x * 256 + tid;
  int v = indeg[i];
  s[tid] = v;
  __syncthreads();
  for (int off = 1; off < 256; off <<= 1) {
    int x = (tid >= off) ? s[tid - off] : 0;
    __syncthreads();
    s[tid] += x;
    __syncthreads();
  }
  rowstart[i] = s[tid] - v;
  if (tid == 255) bsums[blockIdx.x] = s[255];
}

__global__ void scan2_kernel(const int* __restrict__ bsums, int* __restrict__ boffs,
                             int* __restrict__ rowstart) {
  if (threadIdx.x == 0 && blockIdx.x == 0) {
    int run = 0;
    for (int i = 0; i < 640; i++) { boffs[i] = run; run += bsums[i]; }
    rowstart[N_NODES] = run;
  }
}

__global__ __launch_bounds__(256) void scan3_kernel(int* __restrict__ rowstart,
                                                    int* __restrict__ cursor,
                                                    const int* __restrict__ boffs) {
  int i = blockIdx.x * 256 + threadIdx.x;
  int v = rowstart[i] + boffs[blockIdx.x];
  rowstart[i] = v;
  cursor[i] = v;
}

__global__ __launch_bounds__(256) void scatter_kernel(const int* __restrict__ ei,
                                                      int* __restrict__ cursor,
                                                      int* __restrict__ csr_src) {
  int e = blockIdx.x * 256 + threadIdx.x;
  if (e < N_EDGES) {
    int s = ei[e], d = ei[N_EDGES + e];
    int pos = atomicAdd(&cursor[d], 1);
    csr_src[pos] = s;
  }
}

// xb[n, 0:78] = x[n,:] * dinv[n]; cols 78..79 = 0  (padded [N,80] layout)
__global__ __launch_bounds__(256) void cast_scale_kernel(const float* __restrict__ x,
                                                         const float* __restrict__ dinv,
                                                         bf16* __restrict__ xb) {
  int i = blockIdx.x * 256 + threadIdx.x;
  if (i < N_NODES * 80) {
    int n = i / 80, f = i - n * 80;
    float v = (f < 78) ? x[n * 78 + f] * dinv[n] : 0.f;
    xb[i] = __float2bfloat16(v);
  }
}

// ======================= GCN aggregation =======================
// Inputs pre-scaled: hs[n] = h[n] * dinv[n] (pad cols are zero).
// out[n,f] = dn * ( sum_{e:dst=n} hs[src_e,f] + hs[n,f] )
template <int NR>
__global__ __launch_bounds__(256) void agg_kernel(const bf16* __restrict__ hs,
                                                  const float* __restrict__ dinv,
                                                  const int* __restrict__ rowstart,
                                                  const int* __restrict__ csr,
                                                  bf16* __restrict__ out, int F) {
  int node = blockIdx.x * 4 + (threadIdx.x >> 6);
  int lane = threadIdx.x & 63;
  float acc[NR];
#pragma unroll
  for (int r = 0; r < NR; r++) acc[r] = 0.f;
  int st = rowstart[node], en = rowstart[node + 1];
  float dn = dinv[node];
  int e = st;
  for (; e + 4 <= en; e += 4) {
    int s0 = csr[e], s1 = csr[e + 1], s2 = csr[e + 2], s3 = csr[e + 3];
    const bf16* r0 = hs + (size_t)s0 * F;
    const bf16* r1 = hs + (size_t)s1 * F;
    const bf16* r2 = hs + (size_t)s2 * F;
    const bf16* r3 = hs + (size_t)s3 * F;
    float v0[NR], v1[NR], v2[NR], v3[NR];
#pragma unroll
    for (int r = 0; r < NR; r++) {
      int f = lane + 64 * r;
      bool ok = f < F;
      v0[r] = ok ? tofloat(r0[f]) : 0.f;
      v1[r] = ok ? tofloat(r1[f]) : 0.f;
      v2[r] = ok ? tofloat(r2[f]) : 0.f;
      v3[r] = ok ? tofloat(r3[f]) : 0.f;
    }
#pragma unroll
    for (int r = 0; r < NR; r++) acc[r] += (v0[r] + v1[r]) + (v2[r] + v3[r]);
  }
  for (; e < en; e++) {
    int s = csr[e];
    const bf16* hr = hs + (size_t)s * F;
#pragma unroll
    for (int r = 0; r < NR; r++) {
      int f = lane + 64 * r;
      if (f < F) acc[r] += tofloat(hr[f]);
    }
  }
  const bf16* hn = hs + (size_t)node * F;
  bf16* on = out + (size_t)node * F;
#pragma unroll
  for (int r = 0; r < NR; r++) {
    int f = lane + 64 * r;
    if (f < F) {
      float v = dn * (acc[r] + tofloat(hn[f]));
      on[f] = __float2bfloat16(v);
    }
  }
}

// ======================= MFMA GEMM (direct-register, no LDS) =======================
// A [M, lda] bf16 row-major (lda >= K, 16B-aligned rows, pad cols zero)
// Bt [Npad, kpad] bf16: Bt[n*kpad + k] = B[k][n], zeros for k>=K or n>=Nc
// C[row, coff+c] = relu?(A@B + bias)[row,c] * rowScale[row]; cols Nc..ncstore-1 = 0
// Block: 4 waves x (16 rows x NT*16 cols). Grid: (M/64, ceil over cols).
template <int NT, typename TC>
__global__ __launch_bounds__(256) void gemm_mfma_kernel(
    const bf16* __restrict__ A, const bf16* __restrict__ Bt,
    const float* __restrict__ bias, const float* __restrict__ rowScale,
    TC* __restrict__ C, int M, int Nc, int ncstore, int Ksteps, int lda,
    int kpad, int ldc, int coff, int doRelu) {
  int tid = threadIdx.x;
  int w = tid >> 6, lane = tid & 63;
  int quad = lane >> 4, l16 = lane & 15;
  int r0 = blockIdx.x * 64 + w * 16;
  int c0 = blockIdx.y * (NT * 16);
  floatx4 acc[NT];
#pragma unroll
  for (int t = 0; t < NT; t++) acc[t] = (floatx4){0.f, 0.f, 0.f, 0.f};
  const short* Ap = (const short*)A + (size_t)(r0 + l16) * lda + quad * 8;
  const short* Bp = (const short*)Bt + (size_t)(c0 + l16) * kpad + quad * 8;
  for (int s = 0; s < Ksteps; s++) {
    short8 a = *(const short8*)(Ap + s * 32);
#pragma unroll
    for (int t = 0; t < NT; t++) {
      short8 b = *(const short8*)(Bp + (size_t)t * 16 * kpad + s * 32);
      acc[t] = __builtin_amdgcn_mfma_f32_16x16x32_bf16(a, b, acc[t], 0, 0, 0);
    }
  }
#pragma unroll
  for (int t = 0; t < NT; t++) {
    int c = c0 + t * 16 + l16;
    if (c >= ncstore) continue;
    bool valid = c < Nc;
    float bb = (bias && valid) ? bias[c] : 0.f;
#pragma unroll
    for (int r = 0; r < 4; r++) {
      int row = r0 + quad * 4 + r;
      float v = valid ? acc[t][r] + bb : 0.f;
      if (doRelu) v = fmaxf(v, 0.f);
      if (rowScale) v *= rowScale[row];
      storev(&C[(size_t)row * ldc + coff + c], v);
    }
  }
}

// generic weight transpose+pad: W [K,N] f32 -> Bt [Npad, Kpad] bf16
__global__ __launch_bounds__(256) void wtrans_kernel(const float* __restrict__ W,
                                                     bf16* __restrict__ Bt, int K,
                                                     int N, int Kpad, int Npad) {
  int idx = blockIdx.x * 256 + threadIdx.x;
  if (idx < Npad * Kpad) {
    int n = idx / Kpad, k = idx - n * Kpad;
    float v = (k < K && n < N) ? W[(size_t)k * N + n] : 0.f;
    Bt[idx] = __float2bfloat16(v);
  }
}

// Wxt permuted transpose: Bt[o*2944 + (l*128+co)] = Wxt[(co*23+l)*128 + o]
__global__ __launch_bounds__(256) void wxttrans_kernel(const float* __restrict__ Wxt,
                                                       bf16* __restrict__ Bt) {
  int idx = blockIdx.x * 256 + threadIdx.x;
  if (idx < 128 * 2944) {
    int o = idx / 2944, k = idx - o * 2944;
    int l = k >> 7, co = k & 127;
    Bt[idx] = __float2bfloat16(Wxt[((size_t)(co * 23 + l)) * 128 + o]);
  }
}

__global__ __launch_bounds__(256) void castgt_kernel(const float* __restrict__ gt,
                                                     bf16* __restrict__ gtb) {
  int i = blockIdx.x * 256 + threadIdx.x;
  if (i < NB * 256) gtb[i] = __float2bfloat16(gt[i]);
}

// ======= fused layer-3 GCN transform + bias + relu + segment-max (40 nodes/graph) ====
// agg2: [N,160] padded; g out: [B,320] bf16 (zeros in 312..319)
__global__ __launch_bounds__(320) void gcn3_segmax_kernel(const bf16* __restrict__ agg2,
                                                          const float* __restrict__ W3,
                                                          const float* __restrict__ b3,
                                                          bf16* __restrict__ g) {
  __shared__ float a[40][156];
  int gid = blockIdx.x, tid = threadIdx.x;
  for (int i = tid; i < 40 * 156; i += 320) {
    int n = i / 156, k = i - n * 156;
    a[n][k] = tofloat(agg2[((size_t)gid * 40 + n) * 160 + k]);
  }
  __syncthreads();
  if (tid < 312) {
    float acc[40];
#pragma unroll
    for (int n = 0; n < 40; n++) acc[n] = 0.f;
    for (int k = 0; k < 156; k += 4) {
      float w0 = W3[(size_t)k * 312 + tid];
      float w1 = W3[(size_t)(k + 1) * 312 + tid];
      float w2 = W3[(size_t)(k + 2) * 312 + tid];
      float w3 = W3[(size_t)(k + 3) * 312 + tid];
#pragma unroll
      for (int n = 0; n < 40; n++) {
        float4 av = *(const float4*)&a[n][k];
        acc[n] += av.x * w0 + av.y * w1 + av.z * w2 + av.w * w3;
      }
    }
    float m = acc[0];
#pragma unroll
    for (int n = 1; n < 40; n++) m = fmaxf(m, acc[n]);
    g[(size_t)gid * 320 + tid] = __float2bfloat16(fmaxf(m + b3[tid], 0.f));
  } else {
    g[(size_t)gid * 320 + tid] = __float2bfloat16(0.f);  // pad cols 312..319
  }
}

// ======================= weight prep for MFMA convs =======================
template <int CI, int NCO>
__global__ __launch_bounds__(256) void wprep_kernel(const float* __restrict__ kw,
                                                    bf16* __restrict__ Wr) {
  int idx = blockIdx.x * 256 + threadIdx.x;
  if (idx < 8 * CI * NCO) {
    int co = idx % NCO, k = idx / NCO;
    int dl = k / CI, ci = k % CI;
    Wr[idx] = __float2bfloat16(kw[(co * CI + ci) * 8 + dl]);
  }
}

// ======================= conv1: [B,735] f32 -> [B,242,32] bf16 (pos-major) =========
__global__ __launch_bounds__(256) void conv1_kernel(const float* __restrict__ xo,
                                                    const float* __restrict__ k1,
                                                    const float* __restrict__ kb1,
                                                    bf16* __restrict__ out) {
  __shared__ float xin[735];
  int b = blockIdx.x, tid = threadIdx.x;
  for (int i = tid; i < 735; i += 256) xin[i] = xo[b * 735 + i];
  int co = tid & 31;
  float wreg[8];
#pragma unroll
  for (int k = 0; k < 8; k++) wreg[k] = k1[co * 8 + k];
  float bs = kb1[co];
  __syncthreads();
  for (int idx = tid; idx < 242 * 32; idx += 256) {
    int l = idx >> 5;
    int base = l * 3;
    float a0 = bs, a1 = bs, a2 = bs;
#pragma unroll
    for (int k = 0; k < 8; k++) {
      float wv = wreg[k];
      a0 += wv * xin[base + k];
      a1 += wv * xin[base + 1 + k];
      a2 += wv * xin[base + 2 + k];
    }
    out[(size_t)b * (242 * 32) + idx] =
        __float2bfloat16(fmaxf(0.f, fmaxf(a0, fmaxf(a1, a2))));
  }
}

// ======================= MFMA implicit-GEMM conv + bias + relu + pool3 ==============
template <int CI, int LIN, int LPAD, int MT, int LOUT, int G, int NCO>
__global__ __launch_bounds__(256) void convmfma_kernel(const bf16* __restrict__ in,
                                                       const bf16* __restrict__ Wr,
                                                       const float* __restrict__ kb,
                                                       bf16* __restrict__ outp) {
  constexpr int KSTEPS = 8 * CI / 32;
  constexpr int CIP = CI + 8;
  __shared__ __align__(16) bf16 lds_in[G * LPAD * CIP];
  __shared__ bf16 stg[4][MT * 16][16];
  int tid = threadIdx.x;
  int w = tid >> 6, lane = tid & 63;
  int quad = lane >> 4, l16 = lane & 15;
  int bg = blockIdx.x;
  int co0 = blockIdx.y * 64 + w * 16;

  short8 bfrag[KSTEPS];
#pragma unroll
  for (int s = 0; s < KSTEPS; s++) {
#pragma unroll
    for (int j = 0; j < 8; j++) {
      int k = s * 32 + quad * 8 + j;
      bfrag[s][j] = ((const short*)Wr)[k * NCO + co0 + l16];
    }
  }

  const bf16* gin = in + (size_t)bg * G * LIN * CI;
  constexpr int NELEM = G * LIN * CI;
  for (int i = tid; i < NELEM / 8; i += 256) {
    int flat = i * 8;
    int g = flat / (LIN * CI);
    int rem = flat - g * (LIN * CI);
    int row = rem / CI, ci = rem - row * CI;
    *(short8*)&lds_in[(g * LPAD + row) * CIP + ci] = *(const short8*)&gin[flat];
  }
  constexpr int PADE = G * (LPAD - LIN) * CIP;
  for (int i = tid; i < PADE / 8; i += 256) {
    int flat = i * 8;
    int g = flat / ((LPAD - LIN) * CIP);
    int rem = flat - g * ((LPAD - LIN) * CIP);
    short8 z = {0, 0, 0, 0, 0, 0, 0, 0};
    *(short8*)&lds_in[(g * LPAD + LIN) * CIP + rem] = z;
  }
  __syncthreads();

  for (int g = 0; g < G; g++) {
    const bf16* base = &lds_in[g * LPAD * CIP];
#pragma unroll
    for (int mt = 0; mt < MT; mt++) {
      floatx4 acc = {0.f, 0.f, 0.f, 0.f};
      int m = mt * 16 + l16;
#pragma unroll
      for (int s = 0; s < KSTEPS; s++) {
        int kg0 = s * 32 + quad * 8;
        int dl = kg0 / CI;
        int ci0 = kg0 % CI;
        short8 a = *(const short8*)&base[(m + dl) * CIP + ci0];
        acc = __builtin_amdgcn_mfma_f32_16x16x32_bf16(a, bfrag[s], acc, 0, 0, 0);
      }
#pragma unroll
      for (int r = 0; r < 4; r++)
        stg[w][mt * 16 + quad * 4 + r][l16] = __float2bfloat16(acc[r]);
    }
    __syncthreads();
    float bias = kb[co0 + l16];
    for (int it = lane; it < LOUT * 16; it += 64) {
      int l = it >> 4;
      float v0 = __bfloat162float(stg[w][3 * l][l16]);
      float v1 = __bfloat162float(stg[w][3 * l + 1][l16]);
      float v2 = __bfloat162float(stg[w][3 * l + 2][l16]);
      float v = fmaxf(fmaxf(v0, v1), v2) + bias;
      outp[((size_t)(bg * G + g) * LOUT + l) * NCO + co0 + l16] =
          __float2bfloat16(fmaxf(v, 0.f));
    }
    __syncthreads();
  }
}

// ======================= final head =======================
__global__ __launch_bounds__(256) void final_kernel(const float* __restrict__ f2,
                                                    const float* __restrict__ Wo,
                                                    const float* __restrict__ bo,
                                                    float* __restrict__ out) {
  int wid = (blockIdx.x * blockDim.x + threadIdx.x) >> 6;
  int lane = threadIdx.x & 63;
  if (wid >= NB) return;
  float s = f2[wid * 128 + lane] * Wo[lane] + f2[wid * 128 + 64 + lane] * Wo[64 + lane];
  for (int o = 32; o > 0; o >>= 1) s += __shfl_down(s, o);
  if (lane == 0) out[wid] = s + bo[0];
}

// ======================= launch =======================
extern "C" void kernel_launch(void* const* d_in, const int* in_sizes, int n_in,
                              void* d_out, int out_size, void* d_ws, size_t ws_size,
                              hipStream_t stream) {
  const float* x   = (const float*)d_in[0];
  const int*   ei  = (const int*)d_in[1];
  const float* xo  = (const float*)d_in[3];
  const float* W1  = (const float*)d_in[4];  const float* b1  = (const float*)d_in[5];
  const float* W2  = (const float*)d_in[6];  const float* b2  = (const float*)d_in[7];
  const float* W3  = (const float*)d_in[8];  const float* b3  = (const float*)d_in[9];
  const float* Wg1 = (const float*)d_in[10]; const float* bg1 = (const float*)d_in[11];
  const float* Wg2 = (const float*)d_in[12]; const float* bg2 = (const float*)d_in[13];
  const float* k1  = (const float*)d_in[14]; const float* kb1 = (const float*)d_in[15];
  const float* k2  = (const float*)d_in[16]; const float* kb2 = (const float*)d_in[17];
  const float* k3  = (const float*)d_in[18]; const float* kb3 = (const float*)d_in[19];
  const float* Wxt = (const float*)d_in[20]; const float* bxt = (const float*)d_in[21];
  const float* Wf1 = (const float*)d_in[22]; const float* bf1 = (const float*)d_in[23];
  const float* Wf2 = (const float*)d_in[24]; const float* bf2 = (const float*)d_in[25];
  const float* Wo  = (const float*)d_in[26]; const float* bo  = (const float*)d_in[27];
  float* out = (float*)d_out;

  char* ws = (char*)d_ws;
  size_t off = 0;
  auto alloc = [&](size_t bytes) -> void* {
    void* p = ws + off;
    off += (bytes + 255) & ~(size_t)255;
    return p;
  };

  int*   indeg   = (int*)alloc((size_t)N_NODES * 4);
  float* dinv    = (float*)alloc((size_t)N_NODES * 4);
  int*   rowstart= (int*)alloc((size_t)(N_NODES + 1) * 4);
  int*   cursor  = (int*)alloc((size_t)N_NODES * 4);
  int*   bsums   = (int*)alloc(640 * 4);
  int*   boffs   = (int*)alloc(640 * 4);
  int*   csr     = (int*)alloc((size_t)N_EDGES * 4);                 // 10.5 MB
  bf16*  nb1     = (bf16*)alloc((size_t)N_NODES * 160 * 2);          // 52.4 MB
  bf16*  nb2     = (bf16*)alloc((size_t)NB * 32 * 242 * 2);          // 63.4 MB
  bf16*  gb      = (bf16*)alloc((size_t)NB * 320 * 2);
  bf16*  g1b     = (bf16*)alloc((size_t)NB * 1024 * 2);              // also f1b
  float* gt      = (float*)alloc((size_t)NB * 256 * 4);
  bf16*  gtb     = (bf16*)alloc((size_t)NB * 256 * 2);
  float* f2      = (float*)alloc((size_t)NB * 128 * 4);
  bf16*  Wr2     = (bf16*)alloc((size_t)256 * 64 * 2);
  bf16*  Wr3     = (bf16*)alloc((size_t)512 * 128 * 2);
  bf16*  Btw1    = (bf16*)alloc((size_t)80 * 96 * 2);
  bf16*  Btw2    = (bf16*)alloc((size_t)160 * 96 * 2);
  bf16*  Btg1    = (bf16*)alloc((size_t)1024 * 320 * 2);
  bf16*  Btg2    = (bf16*)alloc((size_t)128 * 1024 * 2);
  bf16*  Btxt    = (bf16*)alloc((size_t)128 * 2944 * 2);
  bf16*  Btf1    = (bf16*)alloc((size_t)1024 * 256 * 2);
  bf16*  Btf2    = (bf16*)alloc((size_t)128 * 1024 * 2);

  bf16* xb  = nb2;   // [N,80]
  bf16* h   = nb2;   // h1 [N,80], h2 [N,160]
  bf16* ag  = nb1;   // agg buffers [N,80]/[N,160]
  bf16* c1  = nb2;   // [B,242,32]
  bf16* c2  = nb1;   // [B,78,64]
  bf16* c3  = nb2;   // [B,23,128] flat [B,2944]
  bf16* f1b = g1b;

  // ---- weight prep ----
  wprep_kernel<32, 64><<<(8 * 32 * 64 + 255) / 256, 256, 0, stream>>>(k2, Wr2);
  wprep_kernel<64, 128><<<(8 * 64 * 128 + 255) / 256, 256, 0, stream>>>(k3, Wr3);
  wtrans_kernel<<<(80 * 96 + 255) / 256, 256, 0, stream>>>(W1, Btw1, 78, 78, 96, 80);
  wtrans_kernel<<<(160 * 96 + 255) / 256, 256, 0, stream>>>(W2, Btw2, 78, 156, 96, 160);
  wtrans_kernel<<<(1024 * 320 + 255) / 256, 256, 0, stream>>>(Wg1, Btg1, 312, 1024, 320, 1024);
  wtrans_kernel<<<(128 * 1024 + 255) / 256, 256, 0, stream>>>(Wg2, Btg2, 1024, 128, 1024, 128);
  wxttrans_kernel<<<(128 * 2944 + 255) / 256, 256, 0, stream>>>(Wxt, Btxt);
  wtrans_kernel<<<(1024 * 256 + 255) / 256, 256, 0, stream>>>(Wf1, Btf1, 256, 1024, 256, 1024);
  wtrans_kernel<<<(128 * 1024 + 255) / 256, 256, 0, stream>>>(Wf2, Btf2, 1024, 128, 1024, 128);

  // ---- CSR build + degree norm ----
  zero_kernel<<<N_NODES / 256, 256, 0, stream>>>(indeg);
  count_kernel<<<N_EDGES / 256, 256, 0, stream>>>(ei, indeg);
  dinv_kernel<<<N_NODES / 256, 256, 0, stream>>>(indeg, dinv);
  scan1_kernel<<<640, 256, 0, stream>>>(indeg, rowstart, bsums);
  scan2_kernel<<<1, 64, 0, stream>>>(bsums, boffs, rowstart);
  scan3_kernel<<<640, 256, 0, stream>>>(rowstart, cursor, boffs);
  scatter_kernel<<<N_EDGES / 256, 256, 0, stream>>>(ei, cursor, csr);

  // ---- GCN layers (aggregate-first; dinv folded into stored features) ----
  cast_scale_kernel<<<(N_NODES * 80 + 255) / 256, 256, 0, stream>>>(x, dinv, xb);
  agg_kernel<2><<<N_NODES / 4, 256, 0, stream>>>(xb, dinv, rowstart, csr, ag, 80);
  gemm_mfma_kernel<5, bf16><<<dim3(N_NODES / 64, 1), 256, 0, stream>>>(
      ag, Btw1, b1, dinv, h, N_NODES, 78, 80, 3, 80, 96, 80, 0, 1);
  agg_kernel<2><<<N_NODES / 4, 256, 0, stream>>>(h, dinv, rowstart, csr, ag, 80);
  gemm_mfma_kernel<5, bf16><<<dim3(N_NODES / 64, 2), 256, 0, stream>>>(
      ag, Btw2, b2, dinv, h, N_NODES, 156, 160, 3, 80, 96, 160, 0, 1);
  agg_kernel<3><<<N_NODES / 4, 256, 0, stream>>>(h, dinv, rowstart, csr, ag, 160);
  gcn3_segmax_kernel<<<NB, 320, 0, stream>>>(ag, W3, b3, gb);

  // ---- graph head (MFMA) ----
  gemm_mfma_kernel<4, bf16><<<dim3(NB / 64, 16), 256, 0, stream>>>(
      gb, Btg1, bg1, nullptr, g1b, NB, 1024, 1024, 10, 320, 320, 1024, 0, 1);
  gemm_mfma_kernel<4, float><<<dim3(NB / 64, 2), 256, 0, stream>>>(
      g1b, Btg2, bg2, nullptr, gt, NB, 128, 128, 32, 1024, 1024, 256, 0, 0);

  // ---- conv tower (pos-major, MFMA) ----
  conv1_kernel<<<NB, 256, 0, stream>>>(xo, k1, kb1, c1);
  convmfma_kernel<32, 242, 248, 15, 78, 2, 64>
      <<<dim3(NB / 2, 1), 256, 0, stream>>>(c1, Wr2, kb2, c2);
  convmfma_kernel<64, 78, 88, 5, 23, 4, 128>
      <<<dim3(NB / 4, 2), 256, 0, stream>>>(c2, Wr3, kb3, c3);
  gemm_mfma_kernel<4, float><<<dim3(NB / 64, 2), 256, 0, stream>>>(
      c3, Btxt, bxt, nullptr, gt, NB, 128, 128, 92, 2944, 2944, 256, 128, 0);

  // ---- fused head (MFMA) ----
  castgt_kernel<<<(NB * 256 + 255) / 256, 256, 0, stream>>>(gt, gtb);
  gemm_mfma_kernel<4, bf16><<<dim3(NB / 64, 16), 256, 0, stream>>>(
      gtb, Btf1, bf1, nullptr, f1b, NB, 1024, 1024, 8, 256, 256, 1024, 0, 1);
  gemm_mfma_kernel<4, float><<<dim3(NB / 64, 2), 256, 0, stream>>>(
      f1b, Btf2, bf2, nullptr, f2, NB, 128, 128, 32, 1024, 1024, 128, 0, 1);
  final_kernel<<<NB * 64 / 256, 256, 0, stream>>>(f2, Wo, bo, out);
}

// Round 6
// 1857.455 us; speedup vs baseline: 3.3416x; 1.1424x over previous
//
#include <hip/hip_runtime.h>
#include <hip/hip_bf16.h>

#define N_NODES 163840
#define N_EDGES 2621440
#define NB      4096

typedef __hip_bfloat16 bf16;
typedef __attribute__((ext_vector_type(8))) short short8;
typedef __attribute__((ext_vector_type(4))) float floatx4;

__device__ inline float tofloat(float v) { return v; }
__device__ inline float tofloat(bf16 v) { return __bfloat162float(v); }
__device__ inline void storev(float* p, float v) { *p = v; }
__device__ inline void storev(bf16* p, float v) { *p = __float2bfloat16(v); }

// ======================= graph preprocessing =======================

__global__ __launch_bounds__(256) void zero_kernel(int* __restrict__ p) {
  p[blockIdx.x * 256 + threadIdx.x] = 0;
}

__global__ __launch_bounds__(256) void count_kernel(const int* __restrict__ ei,
                                                    int* __restrict__ indeg) {
  int e = blockIdx.x * 256 + threadIdx.x;
  if (e < N_EDGES) atomicAdd(&indeg[ei[N_EDGES + e]], 1);
}

__global__ __launch_bounds__(256) void dinv_kernel(const int* __restrict__ indeg,
                                                   float* __restrict__ dinv) {
  int i = blockIdx.x * 256 + threadIdx.x;
  if (i < N_NODES) dinv[i] = rsqrtf((float)indeg[i] + 1.0f);
}

__global__ __launch_bounds__(256) void scan1_kernel(const int* __restrict__ indeg,
                                                    int* __restrict__ rowstart,
                                                    int* __restrict__ bsums) {
  __shared__ int s[256];
  int tid = threadIdx.x;
  int i = blockIdx.x * 256 + tid;
  int v = indeg[i];
  s[tid] = v;
  __syncthreads();
  for (int off = 1; off < 256; off <<= 1) {
    int x = (tid >= off) ? s[tid - off] : 0;
    __syncthreads();
    s[tid] += x;
    __syncthreads();
  }
  rowstart[i] = s[tid] - v;
  if (tid == 255) bsums[blockIdx.x] = s[255];
}

__global__ void scan2_kernel(const int* __restrict__ bsums, int* __restrict__ boffs,
                             int* __restrict__ rowstart) {
  if (threadIdx.x == 0 && blockIdx.x == 0) {
    int run = 0;
    for (int i = 0; i < 640; i++) { boffs[i] = run; run += bsums[i]; }
    rowstart[N_NODES] = run;
  }
}

__global__ __launch_bounds__(256) void scan3_kernel(int* __restrict__ rowstart,
                                                    int* __restrict__ cursor,
                                                    const int* __restrict__ boffs) {
  int i = blockIdx.x * 256 + threadIdx.x;
  int v = rowstart[i] + boffs[blockIdx.x];
  rowstart[i] = v;
  cursor[i] = v;
}

__global__ __launch_bounds__(256) void scatter_kernel(const int* __restrict__ ei,
                                                      int* __restrict__ cursor,
                                                      int* __restrict__ csr_src) {
  int e = blockIdx.x * 256 + threadIdx.x;
  if (e < N_EDGES) {
    int s = ei[e], d = ei[N_EDGES + e];
    int pos = atomicAdd(&cursor[d], 1);
    csr_src[pos] = s;
  }
}

// xb[n, 0:78] = x[n,:] * dinv[n]; cols 78..79 = 0  (padded [N,80] layout)
__global__ __launch_bounds__(256) void cast_scale_kernel(const float* __restrict__ x,
                                                         const float* __restrict__ dinv,
                                                         bf16* __restrict__ xb) {
  int i = blockIdx.x * 256 + threadIdx.x;
  if (i < N_NODES * 80) {
    int n = i / 80, f = i - n * 80;
    float v = (f < 78) ? x[n * 78 + f] * dinv[n] : 0.f;
    xb[i] = __float2bfloat16(v);
  }
}

// ======================= GCN aggregation =======================
// Inputs pre-scaled: hs[n] = h[n] * dinv[n] (pad cols are zero).
// out[n,f] = dn * ( sum_{e:dst=n} hs[src_e,f] + hs[n,f] )
// one wave per node; 8-deep edge unroll for memory-level parallelism.
template <int NR>
__global__ __launch_bounds__(256) void agg_kernel(const bf16* __restrict__ hs,
                                                  const float* __restrict__ dinv,
                                                  const int* __restrict__ rowstart,
                                                  const int* __restrict__ csr,
                                                  bf16* __restrict__ out, int F) {
  int node = blockIdx.x * 4 + (threadIdx.x >> 6);
  int lane = threadIdx.x & 63;
  float acc[NR];
#pragma unroll
  for (int r = 0; r < NR; r++) acc[r] = 0.f;
  int st = rowstart[node], en = rowstart[node + 1];
  float dn = dinv[node];
  int e = st;
  for (; e + 8 <= en; e += 8) {
    int sidx[8];
#pragma unroll
    for (int u = 0; u < 8; u++) sidx[u] = csr[e + u];
    float v[8][NR];
#pragma unroll
    for (int u = 0; u < 8; u++) {
      const bf16* rp = hs + (size_t)sidx[u] * F;
#pragma unroll
      for (int r = 0; r < NR; r++) {
        int f = lane + 64 * r;
        v[u][r] = (f < F) ? tofloat(rp[f]) : 0.f;
      }
    }
#pragma unroll
    for (int u = 0; u < 8; u++)
#pragma unroll
      for (int r = 0; r < NR; r++) acc[r] += v[u][r];
  }
  for (; e + 4 <= en; e += 4) {
    int s0 = csr[e], s1 = csr[e + 1], s2 = csr[e + 2], s3 = csr[e + 3];
    const bf16* r0 = hs + (size_t)s0 * F;
    const bf16* r1 = hs + (size_t)s1 * F;
    const bf16* r2 = hs + (size_t)s2 * F;
    const bf16* r3 = hs + (size_t)s3 * F;
    float v0[NR], v1[NR], v2[NR], v3[NR];
#pragma unroll
    for (int r = 0; r < NR; r++) {
      int f = lane + 64 * r;
      bool ok = f < F;
      v0[r] = ok ? tofloat(r0[f]) : 0.f;
      v1[r] = ok ? tofloat(r1[f]) : 0.f;
      v2[r] = ok ? tofloat(r2[f]) : 0.f;
      v3[r] = ok ? tofloat(r3[f]) : 0.f;
    }
#pragma unroll
    for (int r = 0; r < NR; r++) acc[r] += (v0[r] + v1[r]) + (v2[r] + v3[r]);
  }
  for (; e < en; e++) {
    int s = csr[e];
    const bf16* hr = hs + (size_t)s * F;
#pragma unroll
    for (int r = 0; r < NR; r++) {
      int f = lane + 64 * r;
      if (f < F) acc[r] += tofloat(hr[f]);
    }
  }
  const bf16* hn = hs + (size_t)node * F;
  bf16* on = out + (size_t)node * F;
#pragma unroll
  for (int r = 0; r < NR; r++) {
    int f = lane + 64 * r;
    if (f < F) {
      float v = dn * (acc[r] + tofloat(hn[f]));
      on[f] = __float2bfloat16(v);
    }
  }
}

// ======================= MFMA GEMM (direct-register, no LDS) =======================
template <int NT, typename TC>
__global__ __launch_bounds__(256) void gemm_mfma_kernel(
    const bf16* __restrict__ A, const bf16* __restrict__ Bt,
    const float* __restrict__ bias, const float* __restrict__ rowScale,
    TC* __restrict__ C, int M, int Nc, int ncstore, int Ksteps, int lda,
    int kpad, int ldc, int coff, int doRelu) {
  int tid = threadIdx.x;
  int w = tid >> 6, lane = tid & 63;
  int quad = lane >> 4, l16 = lane & 15;
  int r0 = blockIdx.x * 64 + w * 16;
  int c0 = blockIdx.y * (NT * 16);
  floatx4 acc[NT];
#pragma unroll
  for (int t = 0; t < NT; t++) acc[t] = (floatx4){0.f, 0.f, 0.f, 0.f};
  const short* Ap = (const short*)A + (size_t)(r0 + l16) * lda + quad * 8;
  const short* Bp = (const short*)Bt + (size_t)(c0 + l16) * kpad + quad * 8;
  for (int s = 0; s < Ksteps; s++) {
    short8 a = *(const short8*)(Ap + s * 32);
#pragma unroll
    for (int t = 0; t < NT; t++) {
      short8 b = *(const short8*)(Bp + (size_t)t * 16 * kpad + s * 32);
      acc[t] = __builtin_amdgcn_mfma_f32_16x16x32_bf16(a, b, acc[t], 0, 0, 0);
    }
  }
#pragma unroll
  for (int t = 0; t < NT; t++) {
    int c = c0 + t * 16 + l16;
    if (c >= ncstore) continue;
    bool valid = c < Nc;
    float bb = (bias && valid) ? bias[c] : 0.f;
#pragma unroll
    for (int r = 0; r < 4; r++) {
      int row = r0 + quad * 4 + r;
      float v = valid ? acc[t][r] + bb : 0.f;
      if (doRelu) v = fmaxf(v, 0.f);
      if (rowScale) v *= rowScale[row];
      storev(&C[(size_t)row * ldc + coff + c], v);
    }
  }
}

// generic weight transpose+pad: W [K,N] f32 -> Bt [Npad, Kpad] bf16
__global__ __launch_bounds__(256) void wtrans_kernel(const float* __restrict__ W,
                                                     bf16* __restrict__ Bt, int K,
                                                     int N, int Kpad, int Npad) {
  int idx = blockIdx.x * 256 + threadIdx.x;
  if (idx < Npad * Kpad) {
    int n = idx / Kpad, k = idx - n * Kpad;
    float v = (k < K && n < N) ? W[(size_t)k * N + n] : 0.f;
    Bt[idx] = __float2bfloat16(v);
  }
}

// Wxt permuted transpose: Bt[o*2944 + (l*128+co)] = Wxt[(co*23+l)*128 + o]
__global__ __launch_bounds__(256) void wxttrans_kernel(const float* __restrict__ Wxt,
                                                       bf16* __restrict__ Bt) {
  int idx = blockIdx.x * 256 + threadIdx.x;
  if (idx < 128 * 2944) {
    int o = idx / 2944, k = idx - o * 2944;
    int l = k >> 7, co = k & 127;
    Bt[idx] = __float2bfloat16(Wxt[((size_t)(co * 23 + l)) * 128 + o]);
  }
}

__global__ __launch_bounds__(256) void castgt_kernel(const float* __restrict__ gt,
                                                     bf16* __restrict__ gtb) {
  int i = blockIdx.x * 256 + threadIdx.x;
  if (i < NB * 256) gtb[i] = __float2bfloat16(gt[i]);
}

// ======= fused layer-3 GCN transform + bias + relu + segment-max (MFMA) =============
// Block: 4 graphs (160 rows) x 320 cols. agg2 [N,160] bf16; BtW3 [320,160] bf16;
// g out [B,320] bf16 (pad cols produce 0). 4 waves x 80 cols each.
__global__ __launch_bounds__(256) void gcn3_segmax_mfma_kernel(
    const bf16* __restrict__ agg2, const bf16* __restrict__ BtW3,
    const float* __restrict__ b3, bf16* __restrict__ g) {
  __shared__ __align__(16) bf16 a_lds[160 * 168];  // 53.76 KB, row-pad 160->168
  int tid = threadIdx.x;
  int w = tid >> 6, lane = tid & 63;
  int quad = lane >> 4, l16 = lane & 15;
  int g0 = blockIdx.x * 4;

  // B fragments: wave w covers cols w*80 .. w*80+79
  short8 bfrag[5][5];
  const short* Bp = (const short*)BtW3 + (size_t)(w * 80 + l16) * 160 + quad * 8;
#pragma unroll
  for (int nt = 0; nt < 5; nt++)
#pragma unroll
    for (int ks = 0; ks < 5; ks++)
      bfrag[nt][ks] = *(const short8*)(Bp + (size_t)nt * 16 * 160 + ks * 32);

  // stage A: 160 rows x 160 k
  const bf16* src = agg2 + (size_t)g0 * 40 * 160;
  for (int i = tid; i < 160 * 160 / 8; i += 256) {
    int flat = i * 8;
    int row = flat / 160, k = flat - row * 160;
    *(short8*)&a_lds[row * 168 + k] = *(const short8*)&src[flat];
  }
  __syncthreads();

  float gmax[5][4];
#pragma unroll
  for (int nt = 0; nt < 5; nt++)
#pragma unroll
    for (int gi = 0; gi < 4; gi++) gmax[nt][gi] = -3.0e38f;

#pragma unroll
  for (int mt = 0; mt < 10; mt++) {
    floatx4 acc[5];
#pragma unroll
    for (int nt = 0; nt < 5; nt++) acc[nt] = (floatx4){0.f, 0.f, 0.f, 0.f};
#pragma unroll
    for (int ks = 0; ks < 5; ks++) {
      short8 a = *(const short8*)&a_lds[(16 * mt + l16) * 168 + ks * 32 + quad * 8];
#pragma unroll
      for (int nt = 0; nt < 5; nt++)
        acc[nt] = __builtin_amdgcn_mfma_f32_16x16x32_bf16(a, bfrag[nt][ks], acc[nt], 0, 0, 0);
    }
    // rows 16*mt+quad*4 .. +3 lie in one graph (boundaries are multiples of 4)
    int gl = (16 * mt + quad * 4) / 40;
#pragma unroll
    for (int nt = 0; nt < 5; nt++) {
      float m4 = fmaxf(fmaxf(acc[nt][0], acc[nt][1]), fmaxf(acc[nt][2], acc[nt][3]));
#pragma unroll
      for (int gi = 0; gi < 4; gi++)
        if (gl == gi) gmax[nt][gi] = fmaxf(gmax[nt][gi], m4);
    }
  }

  // cross-quad max (lanes with same l16), then bias+relu+store
#pragma unroll
  for (int nt = 0; nt < 5; nt++) {
#pragma unroll
    for (int gi = 0; gi < 4; gi++) {
      float v = gmax[nt][gi];
      v = fmaxf(v, __shfl_xor(v, 16));
      v = fmaxf(v, __shfl_xor(v, 32));
      gmax[nt][gi] = v;
    }
    int c = w * 80 + nt * 16 + l16;
    float bb = (c < 312) ? b3[c] : 0.f;
    float val = fmaxf(gmax[nt][quad] + bb, 0.f);
    g[(size_t)(g0 + quad) * 320 + c] = __float2bfloat16(val);
  }
}

// ======================= weight prep for MFMA convs =======================
template <int CI, int NCO>
__global__ __launch_bounds__(256) void wprep_kernel(const float* __restrict__ kw,
                                                    bf16* __restrict__ Wr) {
  int idx = blockIdx.x * 256 + threadIdx.x;
  if (idx < 8 * CI * NCO) {
    int co = idx % NCO, k = idx / NCO;
    int dl = k / CI, ci = k % CI;
    Wr[idx] = __float2bfloat16(kw[(co * CI + ci) * 8 + dl]);
  }
}

// ======================= conv1: [B,735] f32 -> [B,242,32] bf16 (pos-major) =========
__global__ __launch_bounds__(256) void conv1_kernel(const float* __restrict__ xo,
                                                    const float* __restrict__ k1,
                                                    const float* __restrict__ kb1,
                                                    bf16* __restrict__ out) {
  __shared__ float xin[735];
  int b = blockIdx.x, tid = threadIdx.x;
  for (int i = tid; i < 735; i += 256) xin[i] = xo[b * 735 + i];
  int co = tid & 31;
  float wreg[8];
#pragma unroll
  for (int k = 0; k < 8; k++) wreg[k] = k1[co * 8 + k];
  float bs = kb1[co];
  __syncthreads();
  for (int idx = tid; idx < 242 * 32; idx += 256) {
    int l = idx >> 5;
    int base = l * 3;
    float a0 = bs, a1 = bs, a2 = bs;
#pragma unroll
    for (int k = 0; k < 8; k++) {
      float wv = wreg[k];
      a0 += wv * xin[base + k];
      a1 += wv * xin[base + 1 + k];
      a2 += wv * xin[base + 2 + k];
    }
    out[(size_t)b * (242 * 32) + idx] =
        __float2bfloat16(fmaxf(0.f, fmaxf(a0, fmaxf(a1, a2))));
  }
}

// ======================= MFMA implicit-GEMM conv + bias + relu + pool3 ==============
template <int CI, int LIN, int LPAD, int MT, int LOUT, int G, int NCO>
__global__ __launch_bounds__(256) void convmfma_kernel(const bf16* __restrict__ in,
                                                       const bf16* __restrict__ Wr,
                                                       const float* __restrict__ kb,
                                                       bf16* __restrict__ outp) {
  constexpr int KSTEPS = 8 * CI / 32;
  constexpr int CIP = CI + 8;
  __shared__ __align__(16) bf16 lds_in[G * LPAD * CIP];
  __shared__ bf16 stg[4][MT * 16][16];
  int tid = threadIdx.x;
  int w = tid >> 6, lane = tid & 63;
  int quad = lane >> 4, l16 = lane & 15;
  int bg = blockIdx.x;
  int co0 = blockIdx.y * 64 + w * 16;

  short8 bfrag[KSTEPS];
#pragma unroll
  for (int s = 0; s < KSTEPS; s++) {
#pragma unroll
    for (int j = 0; j < 8; j++) {
      int k = s * 32 + quad * 8 + j;
      bfrag[s][j] = ((const short*)Wr)[k * NCO + co0 + l16];
    }
  }

  const bf16* gin = in + (size_t)bg * G * LIN * CI;
  constexpr int NELEM = G * LIN * CI;
  for (int i = tid; i < NELEM / 8; i += 256) {
    int flat = i * 8;
    int g = flat / (LIN * CI);
    int rem = flat - g * (LIN * CI);
    int row = rem / CI, ci = rem - row * CI;
    *(short8*)&lds_in[(g * LPAD + row) * CIP + ci] = *(const short8*)&gin[flat];
  }
  constexpr int PADE = G * (LPAD - LIN) * CIP;
  for (int i = tid; i < PADE / 8; i += 256) {
    int flat = i * 8;
    int g = flat / ((LPAD - LIN) * CIP);
    int rem = flat - g * ((LPAD - LIN) * CIP);
    short8 z = {0, 0, 0, 0, 0, 0, 0, 0};
    *(short8*)&lds_in[(g * LPAD + LIN) * CIP + rem] = z;
  }
  __syncthreads();

  for (int g = 0; g < G; g++) {
    const bf16* base = &lds_in[g * LPAD * CIP];
#pragma unroll
    for (int mt = 0; mt < MT; mt++) {
      floatx4 acc = {0.f, 0.f, 0.f, 0.f};
      int m = mt * 16 + l16;
#pragma unroll
      for (int s = 0; s < KSTEPS; s++) {
        int kg0 = s * 32 + quad * 8;
        int dl = kg0 / CI;
        int ci0 = kg0 % CI;
        short8 a = *(const short8*)&base[(m + dl) * CIP + ci0];
        acc = __builtin_amdgcn_mfma_f32_16x16x32_bf16(a, bfrag[s], acc, 0, 0, 0);
      }
#pragma unroll
      for (int r = 0; r < 4; r++)
        stg[w][mt * 16 + quad * 4 + r][l16] = __float2bfloat16(acc[r]);
    }
    __syncthreads();
    float bias = kb[co0 + l16];
    for (int it = lane; it < LOUT * 16; it += 64) {
      int l = it >> 4;
      float v0 = __bfloat162float(stg[w][3 * l][l16]);
      float v1 = __bfloat162float(stg[w][3 * l + 1][l16]);
      float v2 = __bfloat162float(stg[w][3 * l + 2][l16]);
      float v = fmaxf(fmaxf(v0, v1), v2) + bias;
      outp[((size_t)(bg * G + g) * LOUT + l) * NCO + co0 + l16] =
          __float2bfloat16(fmaxf(v, 0.f));
    }
    __syncthreads();
  }
}

// ======================= final head =======================
__global__ __launch_bounds__(256) void final_kernel(const float* __restrict__ f2,
                                                    const float* __restrict__ Wo,
                                                    const float* __restrict__ bo,
                                                    float* __restrict__ out) {
  int wid = (blockIdx.x * blockDim.x + threadIdx.x) >> 6;
  int lane = threadIdx.x & 63;
  if (wid >= NB) return;
  float s = f2[wid * 128 + lane] * Wo[lane] + f2[wid * 128 + 64 + lane] * Wo[64 + lane];
  for (int o = 32; o > 0; o >>= 1) s += __shfl_down(s, o);
  if (lane == 0) out[wid] = s + bo[0];
}

// ======================= launch =======================
extern "C" void kernel_launch(void* const* d_in, const int* in_sizes, int n_in,
                              void* d_out, int out_size, void* d_ws, size_t ws_size,
                              hipStream_t stream) {
  const float* x   = (const float*)d_in[0];
  const int*   ei  = (const int*)d_in[1];
  const float* xo  = (const float*)d_in[3];
  const float* W1  = (const float*)d_in[4];  const float* b1  = (const float*)d_in[5];
  const float* W2  = (const float*)d_in[6];  const float* b2  = (const float*)d_in[7];
  const float* W3  = (const float*)d_in[8];  const float* b3  = (const float*)d_in[9];
  const float* Wg1 = (const float*)d_in[10]; const float* bg1 = (const float*)d_in[11];
  const float* Wg2 = (const float*)d_in[12]; const float* bg2 = (const float*)d_in[13];
  const float* k1  = (const float*)d_in[14]; const float* kb1 = (const float*)d_in[15];
  const float* k2  = (const float*)d_in[16]; const float* kb2 = (const float*)d_in[17];
  const float* k3  = (const float*)d_in[18]; const float* kb3 = (const float*)d_in[19];
  const float* Wxt = (const float*)d_in[20]; const float* bxt = (const float*)d_in[21];
  const float* Wf1 = (const float*)d_in[22]; const float* bf1 = (const float*)d_in[23];
  const float* Wf2 = (const float*)d_in[24]; const float* bf2 = (const float*)d_in[25];
  const float* Wo  = (const float*)d_in[26]; const float* bo  = (const float*)d_in[27];
  float* out = (float*)d_out;

  char* ws = (char*)d_ws;
  size_t off = 0;
  auto alloc = [&](size_t bytes) -> void* {
    void* p = ws + off;
    off += (bytes + 255) & ~(size_t)255;
    return p;
  };

  int*   indeg   = (int*)alloc((size_t)N_NODES * 4);
  float* dinv    = (float*)alloc((size_t)N_NODES * 4);
  int*   rowstart= (int*)alloc((size_t)(N_NODES + 1) * 4);
  int*   cursor  = (int*)alloc((size_t)N_NODES * 4);
  int*   bsums   = (int*)alloc(640 * 4);
  int*   boffs   = (int*)alloc(640 * 4);
  int*   csr     = (int*)alloc((size_t)N_EDGES * 4);                 // 10.5 MB
  bf16*  nb1     = (bf16*)alloc((size_t)N_NODES * 160 * 2);          // 52.4 MB
  bf16*  nb2     = (bf16*)alloc((size_t)NB * 32 * 242 * 2);          // 63.4 MB
  bf16*  gb      = (bf16*)alloc((size_t)NB * 320 * 2);
  bf16*  g1b     = (bf16*)alloc((size_t)NB * 1024 * 2);              // also f1b
  float* gt      = (float*)alloc((size_t)NB * 256 * 4);
  bf16*  gtb     = (bf16*)alloc((size_t)NB * 256 * 2);
  float* f2      = (float*)alloc((size_t)NB * 128 * 4);
  bf16*  Wr2     = (bf16*)alloc((size_t)256 * 64 * 2);
  bf16*  Wr3     = (bf16*)alloc((size_t)512 * 128 * 2);
  bf16*  Btw1    = (bf16*)alloc((size_t)80 * 96 * 2);
  bf16*  Btw2    = (bf16*)alloc((size_t)160 * 96 * 2);
  bf16*  BtW3    = (bf16*)alloc((size_t)320 * 160 * 2);
  bf16*  Btg1    = (bf16*)alloc((size_t)1024 * 320 * 2);
  bf16*  Btg2    = (bf16*)alloc((size_t)128 * 1024 * 2);
  bf16*  Btxt    = (bf16*)alloc((size_t)128 * 2944 * 2);
  bf16*  Btf1    = (bf16*)alloc((size_t)1024 * 256 * 2);
  bf16*  Btf2    = (bf16*)alloc((size_t)128 * 1024 * 2);

  bf16* xb  = nb2;   // [N,80]
  bf16* h   = nb2;   // h1 [N,80], h2 [N,160]
  bf16* ag  = nb1;   // agg buffers [N,80]/[N,160]
  bf16* c1  = nb2;   // [B,242,32]
  bf16* c2  = nb1;   // [B,78,64]
  bf16* c3  = nb2;   // [B,23,128] flat [B,2944]
  bf16* f1b = g1b;

  // ---- weight prep ----
  wprep_kernel<32, 64><<<(8 * 32 * 64 + 255) / 256, 256, 0, stream>>>(k2, Wr2);
  wprep_kernel<64, 128><<<(8 * 64 * 128 + 255) / 256, 256, 0, stream>>>(k3, Wr3);
  wtrans_kernel<<<(80 * 96 + 255) / 256, 256, 0, stream>>>(W1, Btw1, 78, 78, 96, 80);
  wtrans_kernel<<<(160 * 96 + 255) / 256, 256, 0, stream>>>(W2, Btw2, 78, 156, 96, 160);
  wtrans_kernel<<<(320 * 160 + 255) / 256, 256, 0, stream>>>(W3, BtW3, 156, 312, 160, 320);
  wtrans_kernel<<<(1024 * 320 + 255) / 256, 256, 0, stream>>>(Wg1, Btg1, 312, 1024, 320, 1024);
  wtrans_kernel<<<(128 * 1024 + 255) / 256, 256, 0, stream>>>(Wg2, Btg2, 1024, 128, 1024, 128);
  wxttrans_kernel<<<(128 * 2944 + 255) / 256, 256, 0, stream>>>(Wxt, Btxt);
  wtrans_kernel<<<(1024 * 256 + 255) / 256, 256, 0, stream>>>(Wf1, Btf1, 256, 1024, 256, 1024);
  wtrans_kernel<<<(128 * 1024 + 255) / 256, 256, 0, stream>>>(Wf2, Btf2, 1024, 128, 1024, 128);

  // ---- CSR build + degree norm ----
  zero_kernel<<<N_NODES / 256, 256, 0, stream>>>(indeg);
  count_kernel<<<N_EDGES / 256, 256, 0, stream>>>(ei, indeg);
  dinv_kernel<<<N_NODES / 256, 256, 0, stream>>>(indeg, dinv);
  scan1_kernel<<<640, 256, 0, stream>>>(indeg, rowstart, bsums);
  scan2_kernel<<<1, 64, 0, stream>>>(bsums, boffs, rowstart);
  scan3_kernel<<<640, 256, 0, stream>>>(rowstart, cursor, boffs);
  scatter_kernel<<<N_EDGES / 256, 256, 0, stream>>>(ei, cursor, csr);

  // ---- GCN layers (aggregate-first; dinv folded into stored features) ----
  cast_scale_kernel<<<(N_NODES * 80 + 255) / 256, 256, 0, stream>>>(x, dinv, xb);
  agg_kernel<2><<<N_NODES / 4, 256, 0, stream>>>(xb, dinv, rowstart, csr, ag, 80);
  gemm_mfma_kernel<5, bf16><<<dim3(N_NODES / 64, 1), 256, 0, stream>>>(
      ag, Btw1, b1, dinv, h, N_NODES, 78, 80, 3, 80, 96, 80, 0, 1);
  agg_kernel<2><<<N_NODES / 4, 256, 0, stream>>>(h, dinv, rowstart, csr, ag, 80);
  gemm_mfma_kernel<5, bf16><<<dim3(N_NODES / 64, 2), 256, 0, stream>>>(
      ag, Btw2, b2, dinv, h, N_NODES, 156, 160, 3, 80, 96, 160, 0, 1);
  agg_kernel<3><<<N_NODES / 4, 256, 0, stream>>>(h, dinv, rowstart, csr, ag, 160);
  gcn3_segmax_mfma_kernel<<<NB / 4, 256, 0, stream>>>(ag, BtW3, b3, gb);

  // ---- graph head (MFMA) ----
  gemm_mfma_kernel<4, bf16><<<dim3(NB / 64, 16), 256, 0, stream>>>(
      gb, Btg1, bg1, nullptr, g1b, NB, 1024, 1024, 10, 320, 320, 1024, 0, 1);
  gemm_mfma_kernel<4, float><<<dim3(NB / 64, 2), 256, 0, stream>>>(
      g1b, Btg2, bg2, nullptr, gt, NB, 128, 128, 32, 1024, 1024, 256, 0, 0);

  // ---- conv tower (pos-major, MFMA) ----
  conv1_kernel<<<NB, 256, 0, stream>>>(xo, k1, kb1, c1);
  convmfma_kernel<32, 242, 248, 15, 78, 2, 64>
      <<<dim3(NB / 2, 1), 256, 0, stream>>>(c1, Wr2, kb2, c2);
  convmfma_kernel<64, 78, 88, 5, 23, 4, 128>
      <<<dim3(NB / 4, 2), 256, 0, stream>>>(c2, Wr3, kb3, c3);
  gemm_mfma_kernel<4, float><<<dim3(NB / 64, 2), 256, 0, stream>>>(
      c3, Btxt, bxt, nullptr, gt, NB, 128, 128, 92, 2944, 2944, 256, 128, 0);

  // ---- fused head (MFMA) ----
  castgt_kernel<<<(NB * 256 + 255) / 256, 256, 0, stream>>>(gt, gtb);
  gemm_mfma_kernel<4, bf16><<<dim3(NB / 64, 16), 256, 0, stream>>>(
      gtb, Btf1, bf1, nullptr, f1b, NB, 1024, 1024, 8, 256, 256, 1024, 0, 1);
  gemm_mfma_kernel<4, float><<<dim3(NB / 64, 2), 256, 0, stream>>>(
      f1b, Btf2, bf2, nullptr, f2, NB, 128, 128, 32, 1024, 1024, 128, 0, 1);
  final_kernel<<<NB * 64 / 256, 256, 0, stream>>>(f2, Wo, bo, out);
}